// Round 15
// baseline (755.586 us; speedup 1.0000x reference)
//
#include <hip/hip_runtime.h>
#include <math.h>

#define Sdim 64
#define Vdim 16
#define NLAYER 5
#define EDdim 16
#define RDdim 16
#define TDdim 64
#define FINdim 160   // 2*S + RD + ED
#define Hdim 96      // S + 2*V
#define NVdim 48     // 3*V

typedef __attribute__((ext_vector_type(8))) short bf16x8;
typedef __attribute__((ext_vector_type(4))) float f32x4;

__device__ __forceinline__ float silu_f(float x) {
    return x / (1.0f + __expf(-x));
}

__device__ __forceinline__ unsigned short f2bf(float x) {
    union { float f; unsigned u; } v; v.f = x;
    unsigned r = v.u + 0x7fffu + ((v.u >> 16) & 1u);
    return (unsigned short)(r >> 16);
}

__device__ __forceinline__ float bf2f(unsigned short u) {
    union { unsigned u; float f; } v; v.u = (unsigned)u << 16;
    return v.f;
}

// ---------------------------------------------------------------------------
// Pack W (10 layer-sets, [160][96] fp32) into MFMA B-fragment bf16 layout.
// Also zeroes counts[2n] (runs before count_all -> saves a memset dispatch).
// ---------------------------------------------------------------------------
__global__ __launch_bounds__(256) void pack_kernel(
    const float* __restrict__ wm, const float* __restrict__ bemb,
    unsigned short* __restrict__ wp, unsigned short* __restrict__ bondbf,
    int* __restrict__ counts, int n2)
{
    int idx = blockIdx.x * 256 + threadIdx.x;
    if (idx < n2) counts[idx] = 0;
    if (idx < 10 * FINdim * Hdim) {
        int ls = idx / (FINdim * Hdim), rem = idx % (FINdim * Hdim);
        int k = rem / Hdim, c = rem % Hdim;
        wp[(size_t)ls * FINdim * Hdim + ((size_t)(k >> 3) * Hdim + c) * 8 + (k & 7)] =
            f2bf(wm[idx]);
    } else if (idx < 10 * FINdim * Hdim + 80) {
        int i = idx - 10 * FINdim * Hdim;
        bondbf[i] = f2bf(bemb[i]);
    }
}

// ---------------------------------------------------------------------------
__global__ __launch_bounds__(64) void temb_kernel(
    const float* __restrict__ t, const float* __restrict__ w1, const float* __restrict__ b1,
    const float* __restrict__ w2, const float* __restrict__ b2, float* __restrict__ temb)
{
    int b = blockIdx.x, j = threadIdx.x;
    __shared__ float row[TDdim];
    __shared__ float hid[TDdim];
    row[j] = t[b * TDdim + j];
    __syncthreads();
    float h = b1[j];
    #pragma unroll 8
    for (int i = 0; i < TDdim; ++i) h = fmaf(row[i], w1[i * TDdim + j], h);
    h = silu_f(h);
    hid[j] = h;
    __syncthreads();
    float o = b2[j];
    #pragma unroll 8
    for (int i = 0; i < TDdim; ++i) o = fmaf(hid[i], w2[i * Sdim + j], o);
    temb[b * Sdim + j] = silu_f(o);
}

// ---------------------------------------------------------------------------
__global__ __launch_bounds__(256) void node_init_kernel(
    const int* __restrict__ x, const int* __restrict__ batch,
    const float* __restrict__ aemb, const float* __restrict__ temb,
    float* __restrict__ sfeat, unsigned short* __restrict__ sbf, int n)
{
    int idx = blockIdx.x * 256 + threadIdx.x;
    if (idx >= n * Sdim) return;
    int node = idx >> 6, j = idx & 63;
    int x0 = x[node * 3 + 0], x1 = x[node * 3 + 1], x2 = x[node * 3 + 2];
    float v = aemb[(0 * 16 + x0) * Sdim + j] + aemb[(16 + x1) * Sdim + j]
            + aemb[(32 + x2) * Sdim + j] + temb[batch[node] * Sdim + j];
    sfeat[idx] = v;
    sbf[idx]   = f2bf(v);
}

// ---------------------------------------------------------------------------
// CSR build for BOTH edge sets in one pass (concatenated edge space).
// ---------------------------------------------------------------------------
__global__ __launch_bounds__(256) void count_all_kernel(
    const int* __restrict__ eil, int EL,
    const int* __restrict__ eig, int EG,
    int* __restrict__ counts, int n)
{
    int idx = blockIdx.x * 256 + threadIdx.x;
    if (idx < EL) {
        atomicAdd(&counts[eil[EL + idx]], 1);
    } else if (idx < EL + EG) {
        int j = idx - EL;
        atomicAdd(&counts[n + eig[EG + j]], 1);
    }
}

// single block, 1024 threads; chunk=32 kept in REGISTERS (int4 x8).
__global__ __launch_bounds__(1024) void scan_kernel(
    const int* __restrict__ counts, int n2,
    int* __restrict__ rowStart, int* __restrict__ cursor)
{
    __shared__ int wsum[16];
    const int t = threadIdx.x;
    const int chunk = n2 >> 10;            // 32
    const int base = t * chunk;

    int4 c[8];
    const int4* c4 = reinterpret_cast<const int4*>(counts + base);
    #pragma unroll
    for (int i = 0; i < 8; ++i) c[i] = c4[i];

    int s = 0;
    #pragma unroll
    for (int i = 0; i < 8; ++i) s += c[i].x + c[i].y + c[i].z + c[i].w;

    const int lane = t & 63, w = t >> 6;
    int sc = s;
    #pragma unroll
    for (int off = 1; off < 64; off <<= 1) {
        int xv = __shfl_up(sc, off);
        if (lane >= off) sc += xv;
    }
    if (lane == 63) wsum[w] = sc;
    __syncthreads();
    int woff = 0;
    for (int i = 0; i < w; ++i) woff += wsum[i];
    int off = woff + sc - s;               // exclusive prefix of this chunk

    #pragma unroll
    for (int i = 0; i < 8; ++i) {
        int v0 = c[i].x, v1 = c[i].y, v2 = c[i].z, v3 = c[i].w;
        int o0 = off, o1 = o0 + v0, o2 = o1 + v1, o3 = o2 + v2;
        *reinterpret_cast<int4*>(rowStart + base + i * 4) = make_int4(o0, o1, o2, o3);
        *reinterpret_cast<int4*>(cursor   + base + i * 4) = make_int4(o0, o1, o2, o3);
        off = o3 + v3;
    }
    if (t == 1023) rowStart[n2] = off;
}

// ---------------------------------------------------------------------------
// Fused scatter + geometry: one pass over all EL+EG edges.
// ---------------------------------------------------------------------------
__global__ __launch_bounds__(256) void scatgeom_kernel(
    const int* __restrict__ eil, const int* __restrict__ eal, int EL,
    const int* __restrict__ eig, const int* __restrict__ eag, int EG,
    int* __restrict__ cursor, int n,
    const float* __restrict__ pos, const unsigned short* __restrict__ bondbf,
    int2* __restrict__ st2, float4* __restrict__ rn4,
    unsigned short* __restrict__ rbfb)
{
    int idx = blockIdx.x * 256 + threadIdx.x;
    if (idx >= EL + EG) return;
    int src, tgt, ea, cbase;
    float cutoff;
    if (idx < EL) {
        src = eil[idx]; tgt = eil[EL + idx]; ea = eal[idx];
        cbase = 0; cutoff = 3.0f;
    } else {
        int j = idx - EL;
        src = eig[j]; tgt = eig[EG + j]; ea = eag[j];
        cbase = n; cutoff = 10.0f;
    }
    int p = atomicAdd(&cursor[cbase + tgt], 1);
    st2[p] = make_int2(src, tgt);

    float rx = pos[3*tgt]-pos[3*src], ry = pos[3*tgt+1]-pos[3*src+1], rz = pos[3*tgt+2]-pos[3*src+2];
    float d = sqrtf(fmaxf(rx*rx + ry*ry + rz*rz, 1e-6f));
    float invd = 1.0f / d;
    rn4[p] = make_float4(rx*invd, ry*invd, rz*invd, d);
    float env = (d < cutoff) ? 0.5f * (__cosf(3.14159265358979f * d / cutoff) + 1.0f) : 0.0f;
    float invw = (float)RDdim / cutoff;
    unsigned int pk[8];
    #pragma unroll
    for (int i2 = 0; i2 < 8; ++i2) {
        float c0 = cutoff * ((float)(2*i2)     / 15.0f);
        float c1 = cutoff * ((float)(2*i2 + 1) / 15.0f);
        float t0 = (d - c0) * invw, t1 = (d - c1) * invw;
        unsigned short b0 = f2bf(__expf(-0.5f * t0 * t0) * env);
        unsigned short b1 = f2bf(__expf(-0.5f * t1 * t1) * env);
        pk[i2] = (unsigned)b0 | ((unsigned)b1 << 16);
    }
    uint4* o = reinterpret_cast<uint4*>(rbfb + (size_t)p * 32);
    o[0] = make_uint4(pk[0], pk[1], pk[2], pk[3]);
    o[1] = make_uint4(pk[4], pk[5], pk[6], pk[7]);
    const uint4* bp = reinterpret_cast<const uint4*>(bondbf + ea * EDdim);
    o[2] = bp[0];
    o[3] = bp[1];
}

// ---------------------------------------------------------------------------
// Kernel A: edge MLP as a pure tall-skinny GEMM (unchanged).
// ---------------------------------------------------------------------------
__global__ __launch_bounds__(256) void edge_mlp_kernel(
    const unsigned short* __restrict__ sbf_in,
    const int2* __restrict__ st2,
    const unsigned short* __restrict__ rbfb,
    const unsigned short* __restrict__ wpk,
    const float* __restrict__ bg,
    unsigned short* __restrict__ hm,
    unsigned short* __restrict__ hv,
    int eOff)
{
    __shared__ __align__(16) unsigned short Wl[FINdim * Hdim];  // 30720 B
    {
        const uint4* s4 = reinterpret_cast<const uint4*>(wpk);
        uint4* d4 = reinterpret_cast<uint4*>(Wl);
        for (int i = threadIdx.x; i < FINdim * Hdim / 8; i += 256) d4[i] = s4[i];
    }
    __syncthreads();

    const int lane = threadIdx.x & 63;
    const int wid  = threadIdx.x >> 6;
    const int l15 = lane & 15, l4 = lane >> 4;
    const int base0 = eOff + blockIdx.x * 128 + wid * 16;
    const int base1 = base0 + 64;

    const int2 st0 = st2[base0 + l15];
    const int2 st1 = st2[base1 + l15];
    bf16x8 a0[5], a1[5];
    {
        const unsigned short* sp = sbf_in + (size_t)st0.x * Sdim;
        const unsigned short* tp = sbf_in + (size_t)st0.y * Sdim;
        a0[0] = *reinterpret_cast<const bf16x8*>(sp + l4 * 8);
        a0[1] = *reinterpret_cast<const bf16x8*>(sp + 32 + l4 * 8);
        a0[2] = *reinterpret_cast<const bf16x8*>(tp + l4 * 8);
        a0[3] = *reinterpret_cast<const bf16x8*>(tp + 32 + l4 * 8);
        a0[4] = *reinterpret_cast<const bf16x8*>(rbfb + (size_t)(base0 + l15) * 32 + l4 * 8);
    }
    {
        const unsigned short* sp = sbf_in + (size_t)st1.x * Sdim;
        const unsigned short* tp = sbf_in + (size_t)st1.y * Sdim;
        a1[0] = *reinterpret_cast<const bf16x8*>(sp + l4 * 8);
        a1[1] = *reinterpret_cast<const bf16x8*>(sp + 32 + l4 * 8);
        a1[2] = *reinterpret_cast<const bf16x8*>(tp + l4 * 8);
        a1[3] = *reinterpret_cast<const bf16x8*>(tp + 32 + l4 * 8);
        a1[4] = *reinterpret_cast<const bf16x8*>(rbfb + (size_t)(base1 + l15) * 32 + l4 * 8);
    }

    f32x4 acc0[6], acc1[6];
    #pragma unroll
    for (int nt = 0; nt < 6; ++nt) {
        acc0[nt] = (f32x4){0.f, 0.f, 0.f, 0.f};
        acc1[nt] = (f32x4){0.f, 0.f, 0.f, 0.f};
    }
    #pragma unroll
    for (int kk = 0; kk < 5; ++kk) {
        #pragma unroll
        for (int nt = 0; nt < 6; ++nt) {
            bf16x8 b = *reinterpret_cast<const bf16x8*>(
                Wl + ((size_t)(kk * 4 + l4) * Hdim + nt * 16 + l15) * 8);
            acc0[nt] = __builtin_amdgcn_mfma_f32_16x16x32_bf16(a0[kk], b, acc0[nt], 0, 0, 0);
            acc1[nt] = __builtin_amdgcn_mfma_f32_16x16x32_bf16(a1[kk], b, acc1[nt], 0, 0, 0);
        }
    }

    #pragma unroll
    for (int nt = 0; nt < 6; ++nt) {
        const float bs = bg[nt * 16 + l15];
        #pragma unroll
        for (int r = 0; r < 4; ++r) {
            const int e0 = base0 + l4 * 4 + r;
            const int e1 = base1 + l4 * 4 + r;
            const unsigned short h0 = f2bf(silu_f(acc0[nt][r] + bs));
            const unsigned short h1 = f2bf(silu_f(acc1[nt][r] + bs));
            if (nt < 4) {
                hm[(size_t)e0 * 64 + nt * 16 + l15] = h0;
                hm[(size_t)e1 * 64 + nt * 16 + l15] = h1;
            } else {
                hv[(size_t)e0 * 32 + (nt - 4) * 16 + l15] = h0;
                hv[(size_t)e1 * 32 + (nt - 4) * 16 + l15] = h1;
            }
        }
    }
}

// ---------------------------------------------------------------------------
// Kernel B v2: 4 WAVES PER NODE.  Wave w handles edges lo+w, lo+w+4, ...
// (serial depth deg/4), partials combined in LDS; update GEMM split across
// waves (16-row slices); wave 0 finishes silu/LN/writes + optional head1.
// ---------------------------------------------------------------------------
__global__ __launch_bounds__(256) void node_agg_kernel(
    const float* __restrict__ s_in, float* __restrict__ s_out,
    unsigned short* __restrict__ sbf_out,
    const float* __restrict__ v_in, float* __restrict__ v_out,
    const int* __restrict__ rowStart, const int2* __restrict__ st2,
    const float* __restrict__ rn4f,
    const unsigned short* __restrict__ hm, const unsigned short* __restrict__ hv,
    const float* __restrict__ wu, const float* __restrict__ bu,
    const float* __restrict__ lng, const float* __restrict__ lnb,
    int do_ln, int v_zero,
    int do_head, const float* __restrict__ wd, const float* __restrict__ wo,
    float* __restrict__ dsc, float* __restrict__ out)
{
    const int node = blockIdx.x;
    const int tid  = threadIdx.x;
    const int lane = tid & 63;
    const int w    = tid >> 6;
    const int l15 = lane & 15, dd = lane >> 4;
    const int lo = rowStart[node], hi = rowStart[node + 1];

    float msum = 0.0f, vsum = 0.0f;
    for (int e = lo + w; e < hi; e += 4) {
        msum += bf2f(hm[(size_t)e * 64 + lane]);
        if (lane < NVdim) {
            float wv1 = bf2f(hv[(size_t)e * 32 + l15]);
            float wv2 = bf2f(hv[(size_t)e * 32 + 16 + l15]);
            float rnd = rn4f[(size_t)e * 4 + dd];
            vsum = fmaf(rnd, wv2, vsum);
            if (!v_zero) {
                float vv = v_in[(size_t)st2[e].x * NVdim + lane];
                vsum = fmaf(vv, wv1, vsum);
            }
        }
    }

    __shared__ float partm[4][64];
    __shared__ float partv[4][48];
    __shared__ float agS[64];
    __shared__ float partd[4][64];

    partm[w][lane] = msum;
    if (lane < NVdim) partv[w][lane] = vsum;
    __syncthreads();

    const float ic = 1.0f / fmaxf((float)(hi - lo), 1.0f);
    if (tid < 64)
        agS[tid] = (partm[0][tid] + partm[1][tid] + partm[2][tid] + partm[3][tid]) * ic;
    __syncthreads();

    {
        float dp = 0.0f;
        #pragma unroll
        for (int i = 0; i < 16; ++i) {
            int ii = w * 16 + i;
            dp = fmaf(agS[ii], wu[ii * Sdim + lane], dp);
        }
        partd[w][lane] = dp;
    }
    __syncthreads();

    if (w == 0) {
        float dot = partd[0][lane] + partd[1][lane] + partd[2][lane] + partd[3][lane];
        float sn = s_in[(size_t)node * Sdim + lane] + silu_f(dot + bu[lane]);
        if (do_ln) {
            float mm = sn;
            #pragma unroll
            for (int off = 32; off >= 1; off >>= 1) mm += __shfl_xor(mm, off);
            mm *= (1.0f / 64.0f);
            float dv = sn - mm;
            float var = dv * dv;
            #pragma unroll
            for (int off = 32; off >= 1; off >>= 1) var += __shfl_xor(var, off);
            var *= (1.0f / 64.0f);
            sn = dv * rsqrtf(var + 1e-5f) * lng[lane] + lnb[lane];
        }
        s_out[(size_t)node * Sdim + lane]   = sn;
        sbf_out[(size_t)node * Sdim + lane] = f2bf(sn);
        float vnew = 0.0f;
        if (lane < NVdim) {
            float vtot = (partv[0][lane] + partv[1][lane] + partv[2][lane] + partv[3][lane]) * ic;
            float vprev = v_zero ? 0.0f : v_in[(size_t)node * NVdim + lane];
            vnew = vprev + vtot;
            v_out[(size_t)node * NVdim + lane] = vnew;
        }
        if (do_head) {
            float val = silu_f(sn) * wd[lane];
            #pragma unroll
            for (int off = 32; off >= 1; off >>= 1) val += __shfl_xor(val, off);
            if (lane == 0) dsc[node] = val;
            float contrib = (lane < NVdim) ? vnew * wo[l15] : 0.0f;
            #pragma unroll
            for (int off = 1; off < 16; off <<= 1) contrib += __shfl_xor(contrib, off);
            if (lane < NVdim && l15 == 0) out[(size_t)node * 3 + dd] = contrib;
        }
    }
}

// ---------------------------------------------------------------------------
// head2: node-parallel over CSR-G; no atomics.  pos[src]-pos[tgt] = -rn*d.
// ---------------------------------------------------------------------------
__global__ __launch_bounds__(256) void head2_kernel(
    const float* __restrict__ dsc, const int* __restrict__ rsG,
    const int2* __restrict__ st2, const float4* __restrict__ rn4,
    float* __restrict__ out, int n)
{
    int t = blockIdx.x * 256 + threadIdx.x;
    if (t >= n) return;
    int lo = rsG[t], hi = rsG[t + 1];
    float dt = dsc[t];
    float ax = 0.f, ay = 0.f, az = 0.f;
    for (int e = lo; e < hi; ++e) {
        float w = dsc[st2[e].x] + dt;
        float4 rn = rn4[e];
        float wd_ = w * rn.w;
        ax -= wd_ * rn.x; ay -= wd_ * rn.y; az -= wd_ * rn.z;
    }
    out[3 * t + 0] += ax;
    out[3 * t + 1] += ay;
    out[3 * t + 2] += az;
}

// ---------------------------------------------------------------------------
extern "C" void kernel_launch(void* const* d_in, const int* in_sizes, int n_in,
                              void* d_out, int out_size, void* d_ws, size_t ws_size,
                              hipStream_t stream)
{
    const int*   x     = (const int*)d_in[0];
    const float* t     = (const float*)d_in[1];
    const float* pos   = (const float*)d_in[2];
    const int*   eil   = (const int*)d_in[3];
    const int*   eig   = (const int*)d_in[4];
    const int*   eal   = (const int*)d_in[5];
    const int*   eag   = (const int*)d_in[6];
    const int*   batch = (const int*)d_in[7];
    const float* aemb  = (const float*)d_in[8];
    const float* bemb  = (const float*)d_in[9];
    const float* t_w1  = (const float*)d_in[10];
    const float* t_b1  = (const float*)d_in[11];
    const float* t_w2  = (const float*)d_in[12];
    const float* t_b2  = (const float*)d_in[13];
    const float* wm    = (const float*)d_in[14];
    const float* bm    = (const float*)d_in[15];
    const float* wu    = (const float*)d_in[16];
    const float* bu    = (const float*)d_in[17];
    const float* lng   = (const float*)d_in[18];
    const float* lnb   = (const float*)d_in[19];
    const float* wd    = (const float*)d_in[20];
    const float* wo    = (const float*)d_in[21];

    const int n  = in_sizes[7];          // 16384
    const int B  = in_sizes[1] / TDdim;  // 64
    const int EL = in_sizes[3] / 2;      // 131072
    const int EG = in_sizes[4] / 2;      // 262144
    const int ET = EL + EG;

    // ---- workspace layout ----
    char* p = (char*)d_ws;
    auto alignup = [](char* q) { return (char*)(((size_t)q + 15) & ~(size_t)15); };

    float* temb = (float*)p;                 p += (size_t)B * Sdim * 4;
    float* dsc  = (float*)p;                 p += (size_t)n * 4;
    float* sA   = (float*)p;                 p += (size_t)n * Sdim * 4;
    float* sB   = (float*)p;                 p += (size_t)n * Sdim * 4;
    float* vA   = (float*)p;                 p += (size_t)n * NVdim * 4;
    float* vB   = (float*)p;                 p += (size_t)n * NVdim * 4;
    int* counts = (int*)p;                   p += (size_t)(2 * n) * 4;
    int* cursor = (int*)p;                   p += (size_t)(2 * n) * 4;
    int* rsAll  = (int*)p;                   p += (size_t)(2 * n + 4) * 4;
    p = alignup(p);
    int2* st2   = (int2*)p;                  p += (size_t)ET * 8;
    p = alignup(p);
    unsigned short* wp     = (unsigned short*)p;  p += (size_t)10 * FINdim * Hdim * 2;
    p = alignup(p);
    unsigned short* bondbf = (unsigned short*)p;  p += 96 * 2;
    p = alignup(p);
    unsigned short* sbfA   = (unsigned short*)p;  p += (size_t)n * Sdim * 2;
    unsigned short* sbfB   = (unsigned short*)p;  p += (size_t)n * Sdim * 2;
    p = alignup(p);
    float4* rn4 = (float4*)p;                p += (size_t)ET * 16;
    unsigned short* rbfb = (unsigned short*)p;    p += (size_t)ET * 32 * 2;
    p = alignup(p);
    unsigned short* hm = (unsigned short*)p; p += (size_t)ET * 64 * 2;
    unsigned short* hv = (unsigned short*)p; p += (size_t)ET * 32 * 2;

    float* out = (float*)d_out;

    // ---- precompute packed weights + init (pack also zeroes counts) ----
    pack_kernel<<<(10 * FINdim * Hdim + 80 + 255) / 256, 256, 0, stream>>>(
        wm, bemb, wp, bondbf, counts, 2 * n);
    temb_kernel<<<B, 64, 0, stream>>>(t, t_w1, t_b1, t_w2, t_b2, temb);
    node_init_kernel<<<(n * Sdim + 255) / 256, 256, 0, stream>>>(x, batch, aemb, temb, sA, sbfA, n);

    // ---- combined CSR build + geometry ----
    count_all_kernel<<<(ET + 255) / 256, 256, 0, stream>>>(eil, EL, eig, EG, counts, n);
    scan_kernel<<<1, 1024, 0, stream>>>(counts, 2 * n, rsAll, cursor);
    scatgeom_kernel<<<(ET + 255) / 256, 256, 0, stream>>>(
        eil, eal, EL, eig, eag, EG, cursor, n, pos, bondbf, st2, rn4, rbfb);

    // ---- layers: edge-MLP GEMM then node aggregate/update ----
    float* s_cur = sA; float* s_nxt = sB;
    float* v_cur = vA; float* v_nxt = vB;
    unsigned short* sb_cur = sbfA; unsigned short* sb_nxt = sbfB;

    for (int l = 0; l < NLAYER; ++l) {
        for (int k = 0; k < 2; ++k) {
            int ls = l * 2 + k;
            const unsigned short* wpk = wp + (size_t)ls * FINdim * Hdim;
            const float* bgk = bm + (size_t)ls * Hdim;
            const float* wuk = wu + (size_t)ls * Sdim * Sdim;
            const float* buk = bu + (size_t)ls * Sdim;
            const int E    = (k == 0) ? EL : EG;
            const int eOff = (k == 0) ? 0 : EL;
            const int* rsk = (k == 0) ? rsAll : rsAll + n;
            const int v_zero = (l == 0 && k == 0) ? 1 : 0;
            const int is_last = (l == NLAYER - 1 && k == 1) ? 1 : 0;

            edge_mlp_kernel<<<E / 128, 256, 0, stream>>>(
                sb_cur, st2, rbfb, wpk, bgk, hm, hv, eOff);
            node_agg_kernel<<<n, 256, 0, stream>>>(
                s_cur, s_nxt, sb_nxt, v_cur, v_nxt,
                rsk, st2, (const float*)rn4, hm, hv,
                wuk, buk, lng + (size_t)l * Sdim, lnb + (size_t)l * Sdim,
                (k == 1) ? 1 : 0, v_zero,
                is_last, wd, wo, dsc, out);

            float* tmp = s_cur; s_cur = s_nxt; s_nxt = tmp;
            tmp = v_cur; v_cur = v_nxt; v_nxt = tmp;
            unsigned short* tb = sb_cur; sb_cur = sb_nxt; sb_nxt = tb;
        }
    }

    head2_kernel<<<(n + 255) / 256, 256, 0, stream>>>(dsc, rsAll + n, st2, rn4, out, n);
}

// Round 16
// 680.732 us; speedup vs baseline: 1.1100x; 1.1100x over previous
//
#include <hip/hip_runtime.h>
#include <math.h>

#define Sdim 64
#define Vdim 16
#define NLAYER 5
#define EDdim 16
#define RDdim 16
#define TDdim 64
#define FINdim 160   // 2*S + RD + ED
#define Hdim 96      // S + 2*V
#define NVdim 48     // 3*V

typedef __attribute__((ext_vector_type(8))) short bf16x8;
typedef __attribute__((ext_vector_type(4))) float f32x4;

__device__ __forceinline__ float silu_f(float x) {
    return x / (1.0f + __expf(-x));
}

__device__ __forceinline__ unsigned short f2bf(float x) {
    union { float f; unsigned u; } v; v.f = x;
    unsigned r = v.u + 0x7fffu + ((v.u >> 16) & 1u);
    return (unsigned short)(r >> 16);
}

__device__ __forceinline__ float bf2f(unsigned short u) {
    union { unsigned u; float f; } v; v.u = (unsigned)u << 16;
    return v.f;
}

// ---------------------------------------------------------------------------
// Pack W (10 layer-sets, [160][96] fp32) into MFMA B-fragment bf16 layout.
// Also zeroes counts[2n].
// ---------------------------------------------------------------------------
__global__ __launch_bounds__(256) void pack_kernel(
    const float* __restrict__ wm, const float* __restrict__ bemb,
    unsigned short* __restrict__ wp, unsigned short* __restrict__ bondbf,
    int* __restrict__ counts, int n2)
{
    int idx = blockIdx.x * 256 + threadIdx.x;
    if (idx < n2) counts[idx] = 0;
    if (idx < 10 * FINdim * Hdim) {
        int ls = idx / (FINdim * Hdim), rem = idx % (FINdim * Hdim);
        int k = rem / Hdim, c = rem % Hdim;
        wp[(size_t)ls * FINdim * Hdim + ((size_t)(k >> 3) * Hdim + c) * 8 + (k & 7)] =
            f2bf(wm[idx]);
    } else if (idx < 10 * FINdim * Hdim + 80) {
        int i = idx - 10 * FINdim * Hdim;
        bondbf[i] = f2bf(bemb[i]);
    }
}

// ---------------------------------------------------------------------------
__global__ __launch_bounds__(64) void temb_kernel(
    const float* __restrict__ t, const float* __restrict__ w1, const float* __restrict__ b1,
    const float* __restrict__ w2, const float* __restrict__ b2, float* __restrict__ temb)
{
    int b = blockIdx.x, j = threadIdx.x;
    __shared__ float row[TDdim];
    __shared__ float hid[TDdim];
    row[j] = t[b * TDdim + j];
    __syncthreads();
    float h = b1[j];
    #pragma unroll 8
    for (int i = 0; i < TDdim; ++i) h = fmaf(row[i], w1[i * TDdim + j], h);
    h = silu_f(h);
    hid[j] = h;
    __syncthreads();
    float o = b2[j];
    #pragma unroll 8
    for (int i = 0; i < TDdim; ++i) o = fmaf(hid[i], w2[i * Sdim + j], o);
    temb[b * Sdim + j] = silu_f(o);
}

// ---------------------------------------------------------------------------
__global__ __launch_bounds__(256) void node_init_kernel(
    const int* __restrict__ x, const int* __restrict__ batch,
    const float* __restrict__ aemb, const float* __restrict__ temb,
    float* __restrict__ sfeat, unsigned short* __restrict__ sbf, int n)
{
    int idx = blockIdx.x * 256 + threadIdx.x;
    if (idx >= n * Sdim) return;
    int node = idx >> 6, j = idx & 63;
    int x0 = x[node * 3 + 0], x1 = x[node * 3 + 1], x2 = x[node * 3 + 2];
    float v = aemb[(0 * 16 + x0) * Sdim + j] + aemb[(16 + x1) * Sdim + j]
            + aemb[(32 + x2) * Sdim + j] + temb[batch[node] * Sdim + j];
    sfeat[idx] = v;
    sbf[idx]   = f2bf(v);
}

// ---------------------------------------------------------------------------
// CSR build for BOTH edge sets in one pass (concatenated edge space).
// ---------------------------------------------------------------------------
__global__ __launch_bounds__(256) void count_all_kernel(
    const int* __restrict__ eil, int EL,
    const int* __restrict__ eig, int EG,
    int* __restrict__ counts, int n)
{
    int idx = blockIdx.x * 256 + threadIdx.x;
    if (idx < EL) {
        atomicAdd(&counts[eil[EL + idx]], 1);
    } else if (idx < EL + EG) {
        int j = idx - EL;
        atomicAdd(&counts[n + eig[EG + j]], 1);
    }
}

// single block, 1024 threads; chunk=32 kept in REGISTERS (int4 x8).
__global__ __launch_bounds__(1024) void scan_kernel(
    const int* __restrict__ counts, int n2,
    int* __restrict__ rowStart, int* __restrict__ cursor)
{
    __shared__ int wsum[16];
    const int t = threadIdx.x;
    const int chunk = n2 >> 10;            // 32
    const int base = t * chunk;

    int4 c[8];
    const int4* c4 = reinterpret_cast<const int4*>(counts + base);
    #pragma unroll
    for (int i = 0; i < 8; ++i) c[i] = c4[i];

    int s = 0;
    #pragma unroll
    for (int i = 0; i < 8; ++i) s += c[i].x + c[i].y + c[i].z + c[i].w;

    const int lane = t & 63, w = t >> 6;
    int sc = s;
    #pragma unroll
    for (int off = 1; off < 64; off <<= 1) {
        int xv = __shfl_up(sc, off);
        if (lane >= off) sc += xv;
    }
    if (lane == 63) wsum[w] = sc;
    __syncthreads();
    int woff = 0;
    for (int i = 0; i < w; ++i) woff += wsum[i];
    int off = woff + sc - s;               // exclusive prefix of this chunk

    #pragma unroll
    for (int i = 0; i < 8; ++i) {
        int v0 = c[i].x, v1 = c[i].y, v2 = c[i].z, v3 = c[i].w;
        int o0 = off, o1 = o0 + v0, o2 = o1 + v1, o3 = o2 + v2;
        *reinterpret_cast<int4*>(rowStart + base + i * 4) = make_int4(o0, o1, o2, o3);
        *reinterpret_cast<int4*>(cursor   + base + i * 4) = make_int4(o0, o1, o2, o3);
        off = o3 + v3;
    }
    if (t == 1023) rowStart[n2] = off;
}

// ---------------------------------------------------------------------------
// Fused scatter + geometry: one pass over all EL+EG edges.
// ---------------------------------------------------------------------------
__global__ __launch_bounds__(256) void scatgeom_kernel(
    const int* __restrict__ eil, const int* __restrict__ eal, int EL,
    const int* __restrict__ eig, const int* __restrict__ eag, int EG,
    int* __restrict__ cursor, int n,
    const float* __restrict__ pos, const unsigned short* __restrict__ bondbf,
    int2* __restrict__ st2, float4* __restrict__ rn4,
    unsigned short* __restrict__ rbfb)
{
    int idx = blockIdx.x * 256 + threadIdx.x;
    if (idx >= EL + EG) return;
    int src, tgt, ea, cbase;
    float cutoff;
    if (idx < EL) {
        src = eil[idx]; tgt = eil[EL + idx]; ea = eal[idx];
        cbase = 0; cutoff = 3.0f;
    } else {
        int j = idx - EL;
        src = eig[j]; tgt = eig[EG + j]; ea = eag[j];
        cbase = n; cutoff = 10.0f;
    }
    int p = atomicAdd(&cursor[cbase + tgt], 1);
    st2[p] = make_int2(src, tgt);

    float rx = pos[3*tgt]-pos[3*src], ry = pos[3*tgt+1]-pos[3*src+1], rz = pos[3*tgt+2]-pos[3*src+2];
    float d = sqrtf(fmaxf(rx*rx + ry*ry + rz*rz, 1e-6f));
    float invd = 1.0f / d;
    rn4[p] = make_float4(rx*invd, ry*invd, rz*invd, d);
    float env = (d < cutoff) ? 0.5f * (__cosf(3.14159265358979f * d / cutoff) + 1.0f) : 0.0f;
    float invw = (float)RDdim / cutoff;
    unsigned int pk[8];
    #pragma unroll
    for (int i2 = 0; i2 < 8; ++i2) {
        float c0 = cutoff * ((float)(2*i2)     / 15.0f);
        float c1 = cutoff * ((float)(2*i2 + 1) / 15.0f);
        float t0 = (d - c0) * invw, t1 = (d - c1) * invw;
        unsigned short b0 = f2bf(__expf(-0.5f * t0 * t0) * env);
        unsigned short b1 = f2bf(__expf(-0.5f * t1 * t1) * env);
        pk[i2] = (unsigned)b0 | ((unsigned)b1 << 16);
    }
    uint4* o = reinterpret_cast<uint4*>(rbfb + (size_t)p * 32);
    o[0] = make_uint4(pk[0], pk[1], pk[2], pk[3]);
    o[1] = make_uint4(pk[4], pk[5], pk[6], pk[7]);
    const uint4* bp = reinterpret_cast<const uint4*>(bondbf + ea * EDdim);
    o[2] = bp[0];
    o[3] = bp[1];
}

// ---------------------------------------------------------------------------
// Kernel A: edge MLP as a pure tall-skinny GEMM (unchanged).
// ---------------------------------------------------------------------------
__global__ __launch_bounds__(256) void edge_mlp_kernel(
    const unsigned short* __restrict__ sbf_in,
    const int2* __restrict__ st2,
    const unsigned short* __restrict__ rbfb,
    const unsigned short* __restrict__ wpk,
    const float* __restrict__ bg,
    unsigned short* __restrict__ hm,
    unsigned short* __restrict__ hv,
    int eOff)
{
    __shared__ __align__(16) unsigned short Wl[FINdim * Hdim];  // 30720 B
    {
        const uint4* s4 = reinterpret_cast<const uint4*>(wpk);
        uint4* d4 = reinterpret_cast<uint4*>(Wl);
        for (int i = threadIdx.x; i < FINdim * Hdim / 8; i += 256) d4[i] = s4[i];
    }
    __syncthreads();

    const int lane = threadIdx.x & 63;
    const int wid  = threadIdx.x >> 6;
    const int l15 = lane & 15, l4 = lane >> 4;
    const int base0 = eOff + blockIdx.x * 128 + wid * 16;
    const int base1 = base0 + 64;

    const int2 st0 = st2[base0 + l15];
    const int2 st1 = st2[base1 + l15];
    bf16x8 a0[5], a1[5];
    {
        const unsigned short* sp = sbf_in + (size_t)st0.x * Sdim;
        const unsigned short* tp = sbf_in + (size_t)st0.y * Sdim;
        a0[0] = *reinterpret_cast<const bf16x8*>(sp + l4 * 8);
        a0[1] = *reinterpret_cast<const bf16x8*>(sp + 32 + l4 * 8);
        a0[2] = *reinterpret_cast<const bf16x8*>(tp + l4 * 8);
        a0[3] = *reinterpret_cast<const bf16x8*>(tp + 32 + l4 * 8);
        a0[4] = *reinterpret_cast<const bf16x8*>(rbfb + (size_t)(base0 + l15) * 32 + l4 * 8);
    }
    {
        const unsigned short* sp = sbf_in + (size_t)st1.x * Sdim;
        const unsigned short* tp = sbf_in + (size_t)st1.y * Sdim;
        a1[0] = *reinterpret_cast<const bf16x8*>(sp + l4 * 8);
        a1[1] = *reinterpret_cast<const bf16x8*>(sp + 32 + l4 * 8);
        a1[2] = *reinterpret_cast<const bf16x8*>(tp + l4 * 8);
        a1[3] = *reinterpret_cast<const bf16x8*>(tp + 32 + l4 * 8);
        a1[4] = *reinterpret_cast<const bf16x8*>(rbfb + (size_t)(base1 + l15) * 32 + l4 * 8);
    }

    f32x4 acc0[6], acc1[6];
    #pragma unroll
    for (int nt = 0; nt < 6; ++nt) {
        acc0[nt] = (f32x4){0.f, 0.f, 0.f, 0.f};
        acc1[nt] = (f32x4){0.f, 0.f, 0.f, 0.f};
    }
    #pragma unroll
    for (int kk = 0; kk < 5; ++kk) {
        #pragma unroll
        for (int nt = 0; nt < 6; ++nt) {
            bf16x8 b = *reinterpret_cast<const bf16x8*>(
                Wl + ((size_t)(kk * 4 + l4) * Hdim + nt * 16 + l15) * 8);
            acc0[nt] = __builtin_amdgcn_mfma_f32_16x16x32_bf16(a0[kk], b, acc0[nt], 0, 0, 0);
            acc1[nt] = __builtin_amdgcn_mfma_f32_16x16x32_bf16(a1[kk], b, acc1[nt], 0, 0, 0);
        }
    }

    #pragma unroll
    for (int nt = 0; nt < 6; ++nt) {
        const float bs = bg[nt * 16 + l15];
        #pragma unroll
        for (int r = 0; r < 4; ++r) {
            const int e0 = base0 + l4 * 4 + r;
            const int e1 = base1 + l4 * 4 + r;
            const unsigned short h0 = f2bf(silu_f(acc0[nt][r] + bs));
            const unsigned short h1 = f2bf(silu_f(acc1[nt][r] + bs));
            if (nt < 4) {
                hm[(size_t)e0 * 64 + nt * 16 + l15] = h0;
                hm[(size_t)e1 * 64 + nt * 16 + l15] = h1;
            } else {
                hv[(size_t)e0 * 32 + (nt - 4) * 16 + l15] = h0;
                hv[(size_t)e1 * 32 + (nt - 4) * 16 + l15] = h1;
            }
        }
    }
}

// ---------------------------------------------------------------------------
// Kernel B (r14 design + unroll x4): ONE WAVE PER NODE, sums in registers,
// 4 independent partial chains; optional fused head1 on the last layer-set.
// ---------------------------------------------------------------------------
__global__ __launch_bounds__(64) void node_agg_kernel(
    const float* __restrict__ s_in, float* __restrict__ s_out,
    unsigned short* __restrict__ sbf_out,
    const float* __restrict__ v_in, float* __restrict__ v_out,
    const int* __restrict__ rowStart, const int2* __restrict__ st2,
    const float* __restrict__ rn4f,
    const unsigned short* __restrict__ hm, const unsigned short* __restrict__ hv,
    const float* __restrict__ wu, const float* __restrict__ bu,
    const float* __restrict__ lng, const float* __restrict__ lnb,
    int do_ln, int v_zero,
    int do_head, const float* __restrict__ wd, const float* __restrict__ wo,
    float* __restrict__ dsc, float* __restrict__ out)
{
    const int node = blockIdx.x;
    const int lane = threadIdx.x;
    const int l15 = lane & 15, dd = lane >> 4;
    const int lo = rowStart[node], hi = rowStart[node + 1];

    float ms0 = 0.f, ms1 = 0.f, ms2 = 0.f, ms3 = 0.f;
    float vs0 = 0.f, vs1 = 0.f, vs2 = 0.f, vs3 = 0.f;
    int e = lo;
    for (; e + 3 < hi; e += 4) {
        ms0 += bf2f(hm[(size_t)(e + 0) * 64 + lane]);
        ms1 += bf2f(hm[(size_t)(e + 1) * 64 + lane]);
        ms2 += bf2f(hm[(size_t)(e + 2) * 64 + lane]);
        ms3 += bf2f(hm[(size_t)(e + 3) * 64 + lane]);
        if (lane < NVdim) {
            #pragma unroll
            for (int q = 0; q < 4; ++q) {
                const int eq = e + q;
                float wv1 = bf2f(hv[(size_t)eq * 32 + l15]);
                float wv2 = bf2f(hv[(size_t)eq * 32 + 16 + l15]);
                float rnd = rn4f[(size_t)eq * 4 + dd];
                float acc = rnd * wv2;
                if (!v_zero) {
                    float vv = v_in[(size_t)st2[eq].x * NVdim + lane];
                    acc = fmaf(vv, wv1, acc);
                }
                if (q == 0) vs0 += acc;
                else if (q == 1) vs1 += acc;
                else if (q == 2) vs2 += acc;
                else vs3 += acc;
            }
        }
    }
    for (; e < hi; ++e) {
        ms0 += bf2f(hm[(size_t)e * 64 + lane]);
        if (lane < NVdim) {
            float wv1 = bf2f(hv[(size_t)e * 32 + l15]);
            float wv2 = bf2f(hv[(size_t)e * 32 + 16 + l15]);
            float rnd = rn4f[(size_t)e * 4 + dd];
            vs0 = fmaf(rnd, wv2, vs0);
            if (!v_zero) {
                float vv = v_in[(size_t)st2[e].x * NVdim + lane];
                vs0 = fmaf(vv, wv1, vs0);
            }
        }
    }
    float msum = (ms0 + ms1) + (ms2 + ms3);
    float vsum = (vs0 + vs1) + (vs2 + vs3);

    __shared__ float ag[64];
    const float ic = 1.0f / fmaxf((float)(hi - lo), 1.0f);
    ag[lane] = msum * ic;            // single wave: in-order LDS, no barrier

    float dot = 0.0f;
    #pragma unroll 8
    for (int i = 0; i < Sdim; ++i) dot = fmaf(ag[i], wu[i * Sdim + lane], dot);
    float sn = s_in[(size_t)node * Sdim + lane] + silu_f(dot + bu[lane]);
    if (do_ln) {
        float mm = sn;
        #pragma unroll
        for (int off = 32; off >= 1; off >>= 1) mm += __shfl_xor(mm, off);
        mm *= (1.0f / 64.0f);
        float dv = sn - mm;
        float var = dv * dv;
        #pragma unroll
        for (int off = 32; off >= 1; off >>= 1) var += __shfl_xor(var, off);
        var *= (1.0f / 64.0f);
        sn = dv * rsqrtf(var + 1e-5f) * lng[lane] + lnb[lane];
    }
    s_out[(size_t)node * Sdim + lane]   = sn;
    sbf_out[(size_t)node * Sdim + lane] = f2bf(sn);
    float vnew = 0.0f;
    if (lane < NVdim) {
        float vprev = v_zero ? 0.0f : v_in[(size_t)node * NVdim + lane];
        vnew = vprev + vsum * ic;
        v_out[(size_t)node * NVdim + lane] = vnew;
    }

    if (do_head) {
        float val = silu_f(sn) * wd[lane];
        #pragma unroll
        for (int off = 32; off >= 1; off >>= 1) val += __shfl_xor(val, off);
        if (lane == 0) dsc[node] = val;
        float contrib = (lane < NVdim) ? vnew * wo[l15] : 0.0f;
        #pragma unroll
        for (int off = 1; off < 16; off <<= 1) contrib += __shfl_xor(contrib, off);
        if (lane < NVdim && l15 == 0) out[(size_t)node * 3 + dd] = contrib;
    }
}

// ---------------------------------------------------------------------------
// head2: node-parallel over CSR-G; no atomics.  pos[src]-pos[tgt] = -rn*d.
// ---------------------------------------------------------------------------
__global__ __launch_bounds__(256) void head2_kernel(
    const float* __restrict__ dsc, const int* __restrict__ rsG,
    const int2* __restrict__ st2, const float4* __restrict__ rn4,
    float* __restrict__ out, int n)
{
    int t = blockIdx.x * 256 + threadIdx.x;
    if (t >= n) return;
    int lo = rsG[t], hi = rsG[t + 1];
    float dt = dsc[t];
    float ax = 0.f, ay = 0.f, az = 0.f;
    for (int e = lo; e < hi; ++e) {
        float w = dsc[st2[e].x] + dt;
        float4 rn = rn4[e];
        float wd_ = w * rn.w;
        ax -= wd_ * rn.x; ay -= wd_ * rn.y; az -= wd_ * rn.z;
    }
    out[3 * t + 0] += ax;
    out[3 * t + 1] += ay;
    out[3 * t + 2] += az;
}

// ---------------------------------------------------------------------------
extern "C" void kernel_launch(void* const* d_in, const int* in_sizes, int n_in,
                              void* d_out, int out_size, void* d_ws, size_t ws_size,
                              hipStream_t stream)
{
    const int*   x     = (const int*)d_in[0];
    const float* t     = (const float*)d_in[1];
    const float* pos   = (const float*)d_in[2];
    const int*   eil   = (const int*)d_in[3];
    const int*   eig   = (const int*)d_in[4];
    const int*   eal   = (const int*)d_in[5];
    const int*   eag   = (const int*)d_in[6];
    const int*   batch = (const int*)d_in[7];
    const float* aemb  = (const float*)d_in[8];
    const float* bemb  = (const float*)d_in[9];
    const float* t_w1  = (const float*)d_in[10];
    const float* t_b1  = (const float*)d_in[11];
    const float* t_w2  = (const float*)d_in[12];
    const float* t_b2  = (const float*)d_in[13];
    const float* wm    = (const float*)d_in[14];
    const float* bm    = (const float*)d_in[15];
    const float* wu    = (const float*)d_in[16];
    const float* bu    = (const float*)d_in[17];
    const float* lng   = (const float*)d_in[18];
    const float* lnb   = (const float*)d_in[19];
    const float* wd    = (const float*)d_in[20];
    const float* wo    = (const float*)d_in[21];

    const int n  = in_sizes[7];          // 16384
    const int B  = in_sizes[1] / TDdim;  // 64
    const int EL = in_sizes[3] / 2;      // 131072
    const int EG = in_sizes[4] / 2;      // 262144
    const int ET = EL + EG;

    // ---- workspace layout ----
    char* p = (char*)d_ws;
    auto alignup = [](char* q) { return (char*)(((size_t)q + 15) & ~(size_t)15); };

    float* temb = (float*)p;                 p += (size_t)B * Sdim * 4;
    float* dsc  = (float*)p;                 p += (size_t)n * 4;
    float* sA   = (float*)p;                 p += (size_t)n * Sdim * 4;
    float* sB   = (float*)p;                 p += (size_t)n * Sdim * 4;
    float* vA   = (float*)p;                 p += (size_t)n * NVdim * 4;
    float* vB   = (float*)p;                 p += (size_t)n * NVdim * 4;
    int* counts = (int*)p;                   p += (size_t)(2 * n) * 4;
    int* cursor = (int*)p;                   p += (size_t)(2 * n) * 4;
    int* rsAll  = (int*)p;                   p += (size_t)(2 * n + 4) * 4;
    p = alignup(p);
    int2* st2   = (int2*)p;                  p += (size_t)ET * 8;
    p = alignup(p);
    unsigned short* wp     = (unsigned short*)p;  p += (size_t)10 * FINdim * Hdim * 2;
    p = alignup(p);
    unsigned short* bondbf = (unsigned short*)p;  p += 96 * 2;
    p = alignup(p);
    unsigned short* sbfA   = (unsigned short*)p;  p += (size_t)n * Sdim * 2;
    unsigned short* sbfB   = (unsigned short*)p;  p += (size_t)n * Sdim * 2;
    p = alignup(p);
    float4* rn4 = (float4*)p;                p += (size_t)ET * 16;
    unsigned short* rbfb = (unsigned short*)p;    p += (size_t)ET * 32 * 2;
    p = alignup(p);
    unsigned short* hm = (unsigned short*)p; p += (size_t)ET * 64 * 2;
    unsigned short* hv = (unsigned short*)p; p += (size_t)ET * 32 * 2;

    float* out = (float*)d_out;

    // ---- precompute packed weights + init (pack also zeroes counts) ----
    pack_kernel<<<(10 * FINdim * Hdim + 80 + 255) / 256, 256, 0, stream>>>(
        wm, bemb, wp, bondbf, counts, 2 * n);
    temb_kernel<<<B, 64, 0, stream>>>(t, t_w1, t_b1, t_w2, t_b2, temb);
    node_init_kernel<<<(n * Sdim + 255) / 256, 256, 0, stream>>>(x, batch, aemb, temb, sA, sbfA, n);

    // ---- combined CSR build + geometry ----
    count_all_kernel<<<(ET + 255) / 256, 256, 0, stream>>>(eil, EL, eig, EG, counts, n);
    scan_kernel<<<1, 1024, 0, stream>>>(counts, 2 * n, rsAll, cursor);
    scatgeom_kernel<<<(ET + 255) / 256, 256, 0, stream>>>(
        eil, eal, EL, eig, eag, EG, cursor, n, pos, bondbf, st2, rn4, rbfb);

    // ---- layers: edge-MLP GEMM then node aggregate/update ----
    float* s_cur = sA; float* s_nxt = sB;
    float* v_cur = vA; float* v_nxt = vB;
    unsigned short* sb_cur = sbfA; unsigned short* sb_nxt = sbfB;

    for (int l = 0; l < NLAYER; ++l) {
        for (int k = 0; k < 2; ++k) {
            int ls = l * 2 + k;
            const unsigned short* wpk = wp + (size_t)ls * FINdim * Hdim;
            const float* bgk = bm + (size_t)ls * Hdim;
            const float* wuk = wu + (size_t)ls * Sdim * Sdim;
            const float* buk = bu + (size_t)ls * Sdim;
            const int E    = (k == 0) ? EL : EG;
            const int eOff = (k == 0) ? 0 : EL;
            const int* rsk = (k == 0) ? rsAll : rsAll + n;
            const int v_zero = (l == 0 && k == 0) ? 1 : 0;
            const int is_last = (l == NLAYER - 1 && k == 1) ? 1 : 0;

            edge_mlp_kernel<<<E / 128, 256, 0, stream>>>(
                sb_cur, st2, rbfb, wpk, bgk, hm, hv, eOff);
            node_agg_kernel<<<n, 64, 0, stream>>>(
                s_cur, s_nxt, sb_nxt, v_cur, v_nxt,
                rsk, st2, (const float*)rn4, hm, hv,
                wuk, buk, lng + (size_t)l * Sdim, lnb + (size_t)l * Sdim,
                (k == 1) ? 1 : 0, v_zero,
                is_last, wd, wo, dsc, out);

            float* tmp = s_cur; s_cur = s_nxt; s_nxt = tmp;
            tmp = v_cur; v_cur = v_nxt; v_nxt = tmp;
            unsigned short* tb = sb_cur; sb_cur = sb_nxt; sb_nxt = tb;
        }
    }

    head2_kernel<<<(n + 255) / 256, 256, 0, stream>>>(dsc, rsAll + n, st2, rn4, out, n);
}

// Round 17
// 605.528 us; speedup vs baseline: 1.2478x; 1.1242x over previous
//
#include <hip/hip_runtime.h>
#include <math.h>

#define Sdim 64
#define Vdim 16
#define NLAYER 5
#define EDdim 16
#define RDdim 16
#define TDdim 64
#define FINdim 160   // 2*S + RD + ED
#define Hdim 96      // S + 2*V
#define NVdim 48     // 3*V

typedef __attribute__((ext_vector_type(8))) short bf16x8;
typedef __attribute__((ext_vector_type(4))) float f32x4;

__device__ __forceinline__ float silu_f(float x) {
    return x / (1.0f + __expf(-x));
}

__device__ __forceinline__ unsigned short f2bf(float x) {
    union { float f; unsigned u; } v; v.f = x;
    unsigned r = v.u + 0x7fffu + ((v.u >> 16) & 1u);
    return (unsigned short)(r >> 16);
}

__device__ __forceinline__ float bf2f(unsigned short u) {
    union { unsigned u; float f; } v; v.u = (unsigned)u << 16;
    return v.f;
}

// ---------------------------------------------------------------------------
// Pack W (10 layer-sets, [160][96] fp32) into MFMA B-fragment bf16 layout.
// Also zeroes counts[2n] (saves a memset dispatch).
// ---------------------------------------------------------------------------
__global__ __launch_bounds__(256) void pack_kernel(
    const float* __restrict__ wm, const float* __restrict__ bemb,
    unsigned short* __restrict__ wp, unsigned short* __restrict__ bondbf,
    int* __restrict__ counts, int n2)
{
    int idx = blockIdx.x * 256 + threadIdx.x;
    if (idx < n2) counts[idx] = 0;
    if (idx < 10 * FINdim * Hdim) {
        int ls = idx / (FINdim * Hdim), rem = idx % (FINdim * Hdim);
        int k = rem / Hdim, c = rem % Hdim;
        wp[(size_t)ls * FINdim * Hdim + ((size_t)(k >> 3) * Hdim + c) * 8 + (k & 7)] =
            f2bf(wm[idx]);
    } else if (idx < 10 * FINdim * Hdim + 80) {
        int i = idx - 10 * FINdim * Hdim;
        bondbf[i] = f2bf(bemb[i]);
    }
}

// ---------------------------------------------------------------------------
__global__ __launch_bounds__(64) void temb_kernel(
    const float* __restrict__ t, const float* __restrict__ w1, const float* __restrict__ b1,
    const float* __restrict__ w2, const float* __restrict__ b2, float* __restrict__ temb)
{
    int b = blockIdx.x, j = threadIdx.x;
    __shared__ float row[TDdim];
    __shared__ float hid[TDdim];
    row[j] = t[b * TDdim + j];
    __syncthreads();
    float h = b1[j];
    #pragma unroll 8
    for (int i = 0; i < TDdim; ++i) h = fmaf(row[i], w1[i * TDdim + j], h);
    h = silu_f(h);
    hid[j] = h;
    __syncthreads();
    float o = b2[j];
    #pragma unroll 8
    for (int i = 0; i < TDdim; ++i) o = fmaf(hid[i], w2[i * Sdim + j], o);
    temb[b * Sdim + j] = silu_f(o);
}

// ---------------------------------------------------------------------------
__global__ __launch_bounds__(256) void node_init_kernel(
    const int* __restrict__ x, const int* __restrict__ batch,
    const float* __restrict__ aemb, const float* __restrict__ temb,
    float* __restrict__ sfeat, unsigned short* __restrict__ sbf, int n)
{
    int idx = blockIdx.x * 256 + threadIdx.x;
    if (idx >= n * Sdim) return;
    int node = idx >> 6, j = idx & 63;
    int x0 = x[node * 3 + 0], x1 = x[node * 3 + 1], x2 = x[node * 3 + 2];
    float v = aemb[(0 * 16 + x0) * Sdim + j] + aemb[(16 + x1) * Sdim + j]
            + aemb[(32 + x2) * Sdim + j] + temb[batch[node] * Sdim + j];
    sfeat[idx] = v;
    sbf[idx]   = f2bf(v);
}

// ---------------------------------------------------------------------------
// CSR build for BOTH edge sets in one pass (concatenated edge space).
// ---------------------------------------------------------------------------
__global__ __launch_bounds__(256) void count_all_kernel(
    const int* __restrict__ eil, int EL,
    const int* __restrict__ eig, int EG,
    int* __restrict__ counts, int n)
{
    int idx = blockIdx.x * 256 + threadIdx.x;
    if (idx < EL) {
        atomicAdd(&counts[eil[EL + idx]], 1);
    } else if (idx < EL + EG) {
        int j = idx - EL;
        atomicAdd(&counts[n + eig[EG + j]], 1);
    }
}

// single block, 1024 threads; chunk=32 kept in REGISTERS (int4 x8).
__global__ __launch_bounds__(1024) void scan_kernel(
    const int* __restrict__ counts, int n2,
    int* __restrict__ rowStart, int* __restrict__ cursor)
{
    __shared__ int wsum[16];
    const int t = threadIdx.x;
    const int chunk = n2 >> 10;            // 32
    const int base = t * chunk;

    int4 c[8];
    const int4* c4 = reinterpret_cast<const int4*>(counts + base);
    #pragma unroll
    for (int i = 0; i < 8; ++i) c[i] = c4[i];

    int s = 0;
    #pragma unroll
    for (int i = 0; i < 8; ++i) s += c[i].x + c[i].y + c[i].z + c[i].w;

    const int lane = t & 63, w = t >> 6;
    int sc = s;
    #pragma unroll
    for (int off = 1; off < 64; off <<= 1) {
        int xv = __shfl_up(sc, off);
        if (lane >= off) sc += xv;
    }
    if (lane == 63) wsum[w] = sc;
    __syncthreads();
    int woff = 0;
    for (int i = 0; i < w; ++i) woff += wsum[i];
    int off = woff + sc - s;               // exclusive prefix of this chunk

    #pragma unroll
    for (int i = 0; i < 8; ++i) {
        int v0 = c[i].x, v1 = c[i].y, v2 = c[i].z, v3 = c[i].w;
        int o0 = off, o1 = o0 + v0, o2 = o1 + v1, o3 = o2 + v2;
        *reinterpret_cast<int4*>(rowStart + base + i * 4) = make_int4(o0, o1, o2, o3);
        *reinterpret_cast<int4*>(cursor   + base + i * 4) = make_int4(o0, o1, o2, o3);
        off = o3 + v3;
    }
    if (t == 1023) rowStart[n2] = off;
}

// ---------------------------------------------------------------------------
// Fused scatter + geometry: one pass over all EL+EG edges.
// ---------------------------------------------------------------------------
__global__ __launch_bounds__(256) void scatgeom_kernel(
    const int* __restrict__ eil, const int* __restrict__ eal, int EL,
    const int* __restrict__ eig, const int* __restrict__ eag, int EG,
    int* __restrict__ cursor, int n,
    const float* __restrict__ pos, const unsigned short* __restrict__ bondbf,
    int2* __restrict__ st2, float4* __restrict__ rn4,
    unsigned short* __restrict__ rbfb)
{
    int idx = blockIdx.x * 256 + threadIdx.x;
    if (idx >= EL + EG) return;
    int src, tgt, ea, cbase;
    float cutoff;
    if (idx < EL) {
        src = eil[idx]; tgt = eil[EL + idx]; ea = eal[idx];
        cbase = 0; cutoff = 3.0f;
    } else {
        int j = idx - EL;
        src = eig[j]; tgt = eig[EG + j]; ea = eag[j];
        cbase = n; cutoff = 10.0f;
    }
    int p = atomicAdd(&cursor[cbase + tgt], 1);
    st2[p] = make_int2(src, tgt);

    float rx = pos[3*tgt]-pos[3*src], ry = pos[3*tgt+1]-pos[3*src+1], rz = pos[3*tgt+2]-pos[3*src+2];
    float d = sqrtf(fmaxf(rx*rx + ry*ry + rz*rz, 1e-6f));
    float invd = 1.0f / d;
    rn4[p] = make_float4(rx*invd, ry*invd, rz*invd, d);
    float env = (d < cutoff) ? 0.5f * (__cosf(3.14159265358979f * d / cutoff) + 1.0f) : 0.0f;
    float invw = (float)RDdim / cutoff;
    unsigned int pk[8];
    #pragma unroll
    for (int i2 = 0; i2 < 8; ++i2) {
        float c0 = cutoff * ((float)(2*i2)     / 15.0f);
        float c1 = cutoff * ((float)(2*i2 + 1) / 15.0f);
        float t0 = (d - c0) * invw, t1 = (d - c1) * invw;
        unsigned short b0 = f2bf(__expf(-0.5f * t0 * t0) * env);
        unsigned short b1 = f2bf(__expf(-0.5f * t1 * t1) * env);
        pk[i2] = (unsigned)b0 | ((unsigned)b1 << 16);
    }
    uint4* o = reinterpret_cast<uint4*>(rbfb + (size_t)p * 32);
    o[0] = make_uint4(pk[0], pk[1], pk[2], pk[3]);
    o[1] = make_uint4(pk[4], pk[5], pk[6], pk[7]);
    const uint4* bp = reinterpret_cast<const uint4*>(bondbf + ea * EDdim);
    o[2] = bp[0];
    o[3] = bp[1];
}

// ---------------------------------------------------------------------------
// Kernel A: edge MLP as a pure tall-skinny GEMM.
// ---------------------------------------------------------------------------
__global__ __launch_bounds__(256) void edge_mlp_kernel(
    const unsigned short* __restrict__ sbf_in,
    const int2* __restrict__ st2,
    const unsigned short* __restrict__ rbfb,
    const unsigned short* __restrict__ wpk,
    const float* __restrict__ bg,
    unsigned short* __restrict__ hm,
    unsigned short* __restrict__ hv,
    int eOff)
{
    __shared__ __align__(16) unsigned short Wl[FINdim * Hdim];  // 30720 B
    {
        const uint4* s4 = reinterpret_cast<const uint4*>(wpk);
        uint4* d4 = reinterpret_cast<uint4*>(Wl);
        for (int i = threadIdx.x; i < FINdim * Hdim / 8; i += 256) d4[i] = s4[i];
    }
    __syncthreads();

    const int lane = threadIdx.x & 63;
    const int wid  = threadIdx.x >> 6;
    const int l15 = lane & 15, l4 = lane >> 4;
    const int base0 = eOff + blockIdx.x * 128 + wid * 16;
    const int base1 = base0 + 64;

    const int2 st0 = st2[base0 + l15];
    const int2 st1 = st2[base1 + l15];
    bf16x8 a0[5], a1[5];
    {
        const unsigned short* sp = sbf_in + (size_t)st0.x * Sdim;
        const unsigned short* tp = sbf_in + (size_t)st0.y * Sdim;
        a0[0] = *reinterpret_cast<const bf16x8*>(sp + l4 * 8);
        a0[1] = *reinterpret_cast<const bf16x8*>(sp + 32 + l4 * 8);
        a0[2] = *reinterpret_cast<const bf16x8*>(tp + l4 * 8);
        a0[3] = *reinterpret_cast<const bf16x8*>(tp + 32 + l4 * 8);
        a0[4] = *reinterpret_cast<const bf16x8*>(rbfb + (size_t)(base0 + l15) * 32 + l4 * 8);
    }
    {
        const unsigned short* sp = sbf_in + (size_t)st1.x * Sdim;
        const unsigned short* tp = sbf_in + (size_t)st1.y * Sdim;
        a1[0] = *reinterpret_cast<const bf16x8*>(sp + l4 * 8);
        a1[1] = *reinterpret_cast<const bf16x8*>(sp + 32 + l4 * 8);
        a1[2] = *reinterpret_cast<const bf16x8*>(tp + l4 * 8);
        a1[3] = *reinterpret_cast<const bf16x8*>(tp + 32 + l4 * 8);
        a1[4] = *reinterpret_cast<const bf16x8*>(rbfb + (size_t)(base1 + l15) * 32 + l4 * 8);
    }

    f32x4 acc0[6], acc1[6];
    #pragma unroll
    for (int nt = 0; nt < 6; ++nt) {
        acc0[nt] = (f32x4){0.f, 0.f, 0.f, 0.f};
        acc1[nt] = (f32x4){0.f, 0.f, 0.f, 0.f};
    }
    #pragma unroll
    for (int kk = 0; kk < 5; ++kk) {
        #pragma unroll
        for (int nt = 0; nt < 6; ++nt) {
            bf16x8 b = *reinterpret_cast<const bf16x8*>(
                Wl + ((size_t)(kk * 4 + l4) * Hdim + nt * 16 + l15) * 8);
            acc0[nt] = __builtin_amdgcn_mfma_f32_16x16x32_bf16(a0[kk], b, acc0[nt], 0, 0, 0);
            acc1[nt] = __builtin_amdgcn_mfma_f32_16x16x32_bf16(a1[kk], b, acc1[nt], 0, 0, 0);
        }
    }

    #pragma unroll
    for (int nt = 0; nt < 6; ++nt) {
        const float bs = bg[nt * 16 + l15];
        #pragma unroll
        for (int r = 0; r < 4; ++r) {
            const int e0 = base0 + l4 * 4 + r;
            const int e1 = base1 + l4 * 4 + r;
            const unsigned short h0 = f2bf(silu_f(acc0[nt][r] + bs));
            const unsigned short h1 = f2bf(silu_f(acc1[nt][r] + bs));
            if (nt < 4) {
                hm[(size_t)e0 * 64 + nt * 16 + l15] = h0;
                hm[(size_t)e1 * 64 + nt * 16 + l15] = h1;
            } else {
                hv[(size_t)e0 * 32 + (nt - 4) * 16 + l15] = h0;
                hv[(size_t)e1 * 32 + (nt - 4) * 16 + l15] = h1;
            }
        }
    }
}

// ---------------------------------------------------------------------------
// Kernel B (r14 form): ONE WAVE PER NODE, x2 unroll with explicit per-edge
// temporaries, sums in registers; fused head1 on the last layer-set.
// ---------------------------------------------------------------------------
__global__ __launch_bounds__(64) void node_agg_kernel(
    const float* __restrict__ s_in, float* __restrict__ s_out,
    unsigned short* __restrict__ sbf_out,
    const float* __restrict__ v_in, float* __restrict__ v_out,
    const int* __restrict__ rowStart, const int2* __restrict__ st2,
    const float* __restrict__ rn4f,
    const unsigned short* __restrict__ hm, const unsigned short* __restrict__ hv,
    const float* __restrict__ wu, const float* __restrict__ bu,
    const float* __restrict__ lng, const float* __restrict__ lnb,
    int do_ln, int v_zero,
    int do_head, const float* __restrict__ wd, const float* __restrict__ wo,
    float* __restrict__ dsc, float* __restrict__ out)
{
    const int node = blockIdx.x;
    const int lane = threadIdx.x;
    const int l15 = lane & 15, dd = lane >> 4;
    const int lo = rowStart[node], hi = rowStart[node + 1];

    float msum0 = 0.0f, msum1 = 0.0f, vsum0 = 0.0f, vsum1 = 0.0f;
    int e = lo;
    for (; e + 1 < hi; e += 2) {
        msum0 += bf2f(hm[(size_t)e * 64 + lane]);
        msum1 += bf2f(hm[(size_t)(e + 1) * 64 + lane]);
        if (lane < NVdim) {
            float wv1a = bf2f(hv[(size_t)e * 32 + l15]);
            float wv2a = bf2f(hv[(size_t)e * 32 + 16 + l15]);
            float rnda = rn4f[(size_t)e * 4 + dd];
            float wv1b = bf2f(hv[(size_t)(e + 1) * 32 + l15]);
            float wv2b = bf2f(hv[(size_t)(e + 1) * 32 + 16 + l15]);
            float rndb = rn4f[(size_t)(e + 1) * 4 + dd];
            vsum0 = fmaf(rnda, wv2a, vsum0);
            vsum1 = fmaf(rndb, wv2b, vsum1);
            if (!v_zero) {
                float vva = v_in[(size_t)st2[e].x * NVdim + lane];
                float vvb = v_in[(size_t)st2[e + 1].x * NVdim + lane];
                vsum0 = fmaf(vva, wv1a, vsum0);
                vsum1 = fmaf(vvb, wv1b, vsum1);
            }
        }
    }
    if (e < hi) {
        msum0 += bf2f(hm[(size_t)e * 64 + lane]);
        if (lane < NVdim) {
            float wv1 = bf2f(hv[(size_t)e * 32 + l15]);
            float wv2 = bf2f(hv[(size_t)e * 32 + 16 + l15]);
            float rnd = rn4f[(size_t)e * 4 + dd];
            vsum0 = fmaf(rnd, wv2, vsum0);
            if (!v_zero) {
                float vv = v_in[(size_t)st2[e].x * NVdim + lane];
                vsum0 = fmaf(vv, wv1, vsum0);
            }
        }
    }
    float msum = msum0 + msum1;
    float vsum = vsum0 + vsum1;

    __shared__ float ag[64];
    const float ic = 1.0f / fmaxf((float)(hi - lo), 1.0f);
    ag[lane] = msum * ic;            // single wave: in-order LDS, no barrier

    float dot = 0.0f;
    #pragma unroll 8
    for (int i = 0; i < Sdim; ++i) dot = fmaf(ag[i], wu[i * Sdim + lane], dot);
    float sn = s_in[(size_t)node * Sdim + lane] + silu_f(dot + bu[lane]);
    if (do_ln) {
        float mm = sn;
        #pragma unroll
        for (int off = 32; off >= 1; off >>= 1) mm += __shfl_xor(mm, off);
        mm *= (1.0f / 64.0f);
        float dv = sn - mm;
        float var = dv * dv;
        #pragma unroll
        for (int off = 32; off >= 1; off >>= 1) var += __shfl_xor(var, off);
        var *= (1.0f / 64.0f);
        sn = dv * rsqrtf(var + 1e-5f) * lng[lane] + lnb[lane];
    }
    s_out[(size_t)node * Sdim + lane]   = sn;
    sbf_out[(size_t)node * Sdim + lane] = f2bf(sn);
    float vnew = 0.0f;
    if (lane < NVdim) {
        float vprev = v_zero ? 0.0f : v_in[(size_t)node * NVdim + lane];
        vnew = vprev + vsum * ic;
        v_out[(size_t)node * NVdim + lane] = vnew;
    }

    if (do_head) {
        float val = silu_f(sn) * wd[lane];
        #pragma unroll
        for (int off = 32; off >= 1; off >>= 1) val += __shfl_xor(val, off);
        if (lane == 0) dsc[node] = val;
        float contrib = (lane < NVdim) ? vnew * wo[l15] : 0.0f;
        #pragma unroll
        for (int off = 1; off < 16; off <<= 1) contrib += __shfl_xor(contrib, off);
        if (lane < NVdim && l15 == 0) out[(size_t)node * 3 + dd] = contrib;
    }
}

// ---------------------------------------------------------------------------
// head2: node-parallel over CSR-G; no atomics.  pos[src]-pos[tgt] = -rn*d.
// ---------------------------------------------------------------------------
__global__ __launch_bounds__(256) void head2_kernel(
    const float* __restrict__ dsc, const int* __restrict__ rsG,
    const int2* __restrict__ st2, const float4* __restrict__ rn4,
    float* __restrict__ out, int n)
{
    int t = blockIdx.x * 256 + threadIdx.x;
    if (t >= n) return;
    int lo = rsG[t], hi = rsG[t + 1];
    float dt = dsc[t];
    float ax = 0.f, ay = 0.f, az = 0.f;
    for (int e = lo; e < hi; ++e) {
        float w = dsc[st2[e].x] + dt;
        float4 rn = rn4[e];
        float wd_ = w * rn.w;
        ax -= wd_ * rn.x; ay -= wd_ * rn.y; az -= wd_ * rn.z;
    }
    out[3 * t + 0] += ax;
    out[3 * t + 1] += ay;
    out[3 * t + 2] += az;
}

// ---------------------------------------------------------------------------
extern "C" void kernel_launch(void* const* d_in, const int* in_sizes, int n_in,
                              void* d_out, int out_size, void* d_ws, size_t ws_size,
                              hipStream_t stream)
{
    const int*   x     = (const int*)d_in[0];
    const float* t     = (const float*)d_in[1];
    const float* pos   = (const float*)d_in[2];
    const int*   eil   = (const int*)d_in[3];
    const int*   eig   = (const int*)d_in[4];
    const int*   eal   = (const int*)d_in[5];
    const int*   eag   = (const int*)d_in[6];
    const int*   batch = (const int*)d_in[7];
    const float* aemb  = (const float*)d_in[8];
    const float* bemb  = (const float*)d_in[9];
    const float* t_w1  = (const float*)d_in[10];
    const float* t_b1  = (const float*)d_in[11];
    const float* t_w2  = (const float*)d_in[12];
    const float* t_b2  = (const float*)d_in[13];
    const float* wm    = (const float*)d_in[14];
    const float* bm    = (const float*)d_in[15];
    const float* wu    = (const float*)d_in[16];
    const float* bu    = (const float*)d_in[17];
    const float* lng   = (const float*)d_in[18];
    const float* lnb   = (const float*)d_in[19];
    const float* wd    = (const float*)d_in[20];
    const float* wo    = (const float*)d_in[21];

    const int n  = in_sizes[7];          // 16384
    const int B  = in_sizes[1] / TDdim;  // 64
    const int EL = in_sizes[3] / 2;      // 131072
    const int EG = in_sizes[4] / 2;      // 262144
    const int ET = EL + EG;

    // ---- workspace layout ----
    char* p = (char*)d_ws;
    auto alignup = [](char* q) { return (char*)(((size_t)q + 15) & ~(size_t)15); };

    float* temb = (float*)p;                 p += (size_t)B * Sdim * 4;
    float* dsc  = (float*)p;                 p += (size_t)n * 4;
    float* sA   = (float*)p;                 p += (size_t)n * Sdim * 4;
    float* sB   = (float*)p;                 p += (size_t)n * Sdim * 4;
    float* vA   = (float*)p;                 p += (size_t)n * NVdim * 4;
    float* vB   = (float*)p;                 p += (size_t)n * NVdim * 4;
    int* counts = (int*)p;                   p += (size_t)(2 * n) * 4;
    int* cursor = (int*)p;                   p += (size_t)(2 * n) * 4;
    int* rsAll  = (int*)p;                   p += (size_t)(2 * n + 4) * 4;
    p = alignup(p);
    int2* st2   = (int2*)p;                  p += (size_t)ET * 8;
    p = alignup(p);
    unsigned short* wp     = (unsigned short*)p;  p += (size_t)10 * FINdim * Hdim * 2;
    p = alignup(p);
    unsigned short* bondbf = (unsigned short*)p;  p += 96 * 2;
    p = alignup(p);
    unsigned short* sbfA   = (unsigned short*)p;  p += (size_t)n * Sdim * 2;
    unsigned short* sbfB   = (unsigned short*)p;  p += (size_t)n * Sdim * 2;
    p = alignup(p);
    float4* rn4 = (float4*)p;                p += (size_t)ET * 16;
    unsigned short* rbfb = (unsigned short*)p;    p += (size_t)ET * 32 * 2;
    p = alignup(p);
    unsigned short* hm = (unsigned short*)p; p += (size_t)ET * 64 * 2;
    unsigned short* hv = (unsigned short*)p; p += (size_t)ET * 32 * 2;

    float* out = (float*)d_out;

    // ---- precompute packed weights + init (pack also zeroes counts) ----
    pack_kernel<<<(10 * FINdim * Hdim + 80 + 255) / 256, 256, 0, stream>>>(
        wm, bemb, wp, bondbf, counts, 2 * n);
    temb_kernel<<<B, 64, 0, stream>>>(t, t_w1, t_b1, t_w2, t_b2, temb);
    node_init_kernel<<<(n * Sdim + 255) / 256, 256, 0, stream>>>(x, batch, aemb, temb, sA, sbfA, n);

    // ---- combined CSR build + geometry ----
    count_all_kernel<<<(ET + 255) / 256, 256, 0, stream>>>(eil, EL, eig, EG, counts, n);
    scan_kernel<<<1, 1024, 0, stream>>>(counts, 2 * n, rsAll, cursor);
    scatgeom_kernel<<<(ET + 255) / 256, 256, 0, stream>>>(
        eil, eal, EL, eig, eag, EG, cursor, n, pos, bondbf, st2, rn4, rbfb);

    // ---- layers: edge-MLP GEMM then node aggregate/update ----
    float* s_cur = sA; float* s_nxt = sB;
    float* v_cur = vA; float* v_nxt = vB;
    unsigned short* sb_cur = sbfA; unsigned short* sb_nxt = sbfB;

    for (int l = 0; l < NLAYER; ++l) {
        for (int k = 0; k < 2; ++k) {
            int ls = l * 2 + k;
            const unsigned short* wpk = wp + (size_t)ls * FINdim * Hdim;
            const float* bgk = bm + (size_t)ls * Hdim;
            const float* wuk = wu + (size_t)ls * Sdim * Sdim;
            const float* buk = bu + (size_t)ls * Sdim;
            const int E    = (k == 0) ? EL : EG;
            const int eOff = (k == 0) ? 0 : EL;
            const int* rsk = (k == 0) ? rsAll : rsAll + n;
            const int v_zero = (l == 0 && k == 0) ? 1 : 0;
            const int is_last = (l == NLAYER - 1 && k == 1) ? 1 : 0;

            edge_mlp_kernel<<<E / 128, 256, 0, stream>>>(
                sb_cur, st2, rbfb, wpk, bgk, hm, hv, eOff);
            node_agg_kernel<<<n, 64, 0, stream>>>(
                s_cur, s_nxt, sb_nxt, v_cur, v_nxt,
                rsk, st2, (const float*)rn4, hm, hv,
                wuk, buk, lng + (size_t)l * Sdim, lnb + (size_t)l * Sdim,
                (k == 1) ? 1 : 0, v_zero,
                is_last, wd, wo, dsc, out);

            float* tmp = s_cur; s_cur = s_nxt; s_nxt = tmp;
            tmp = v_cur; v_cur = v_nxt; v_nxt = tmp;
            unsigned short* tb = sb_cur; sb_cur = sb_nxt; sb_nxt = tb;
        }
    }

    head2_kernel<<<(n + 255) / 256, 256, 0, stream>>>(dsc, rsAll + n, st2, rn4, out, n);
}

// Round 18
// 605.441 us; speedup vs baseline: 1.2480x; 1.0001x over previous
//
#include <hip/hip_runtime.h>
#include <math.h>

#define Sdim 64
#define Vdim 16
#define NLAYER 5
#define EDdim 16
#define RDdim 16
#define TDdim 64
#define FINdim 160   // 2*S + RD + ED
#define Hdim 96      // S + 2*V
#define NVdim 48     // 3*V

typedef __attribute__((ext_vector_type(8))) short bf16x8;
typedef __attribute__((ext_vector_type(4))) float f32x4;

__device__ __forceinline__ float silu_f(float x) {
    return x / (1.0f + __expf(-x));
}

__device__ __forceinline__ unsigned short f2bf(float x) {
    union { float f; unsigned u; } v; v.f = x;
    unsigned r = v.u + 0x7fffu + ((v.u >> 16) & 1u);
    return (unsigned short)(r >> 16);
}

__device__ __forceinline__ float bf2f(unsigned short u) {
    union { unsigned u; float f; } v; v.u = (unsigned)u << 16;
    return v.f;
}

// ---------------------------------------------------------------------------
// Pack W (10 layer-sets, [160][96] fp32) into MFMA B-fragment bf16 layout.
// Also zeroes counts[2n] (saves a memset dispatch).
// ---------------------------------------------------------------------------
__global__ __launch_bounds__(256) void pack_kernel(
    const float* __restrict__ wm, const float* __restrict__ bemb,
    unsigned short* __restrict__ wp, unsigned short* __restrict__ bondbf,
    int* __restrict__ counts, int n2)
{
    int idx = blockIdx.x * 256 + threadIdx.x;
    if (idx < n2) counts[idx] = 0;
    if (idx < 10 * FINdim * Hdim) {
        int ls = idx / (FINdim * Hdim), rem = idx % (FINdim * Hdim);
        int k = rem / Hdim, c = rem % Hdim;
        wp[(size_t)ls * FINdim * Hdim + ((size_t)(k >> 3) * Hdim + c) * 8 + (k & 7)] =
            f2bf(wm[idx]);
    } else if (idx < 10 * FINdim * Hdim + 80) {
        int i = idx - 10 * FINdim * Hdim;
        bondbf[i] = f2bf(bemb[i]);
    }
}

// ---------------------------------------------------------------------------
__global__ __launch_bounds__(64) void temb_kernel(
    const float* __restrict__ t, const float* __restrict__ w1, const float* __restrict__ b1,
    const float* __restrict__ w2, const float* __restrict__ b2, float* __restrict__ temb)
{
    int b = blockIdx.x, j = threadIdx.x;
    __shared__ float row[TDdim];
    __shared__ float hid[TDdim];
    row[j] = t[b * TDdim + j];
    __syncthreads();
    float h = b1[j];
    #pragma unroll 8
    for (int i = 0; i < TDdim; ++i) h = fmaf(row[i], w1[i * TDdim + j], h);
    h = silu_f(h);
    hid[j] = h;
    __syncthreads();
    float o = b2[j];
    #pragma unroll 8
    for (int i = 0; i < TDdim; ++i) o = fmaf(hid[i], w2[i * Sdim + j], o);
    temb[b * Sdim + j] = silu_f(o);
}

// ---------------------------------------------------------------------------
__global__ __launch_bounds__(256) void node_init_kernel(
    const int* __restrict__ x, const int* __restrict__ batch,
    const float* __restrict__ aemb, const float* __restrict__ temb,
    float* __restrict__ sfeat, unsigned short* __restrict__ sbf, int n)
{
    int idx = blockIdx.x * 256 + threadIdx.x;
    if (idx >= n * Sdim) return;
    int node = idx >> 6, j = idx & 63;
    int x0 = x[node * 3 + 0], x1 = x[node * 3 + 1], x2 = x[node * 3 + 2];
    float v = aemb[(0 * 16 + x0) * Sdim + j] + aemb[(16 + x1) * Sdim + j]
            + aemb[(32 + x2) * Sdim + j] + temb[batch[node] * Sdim + j];
    sfeat[idx] = v;
    sbf[idx]   = f2bf(v);
}

// ---------------------------------------------------------------------------
// CSR build for BOTH edge sets in one pass (concatenated edge space).
// ---------------------------------------------------------------------------
__global__ __launch_bounds__(256) void count_all_kernel(
    const int* __restrict__ eil, int EL,
    const int* __restrict__ eig, int EG,
    int* __restrict__ counts, int n)
{
    int idx = blockIdx.x * 256 + threadIdx.x;
    if (idx < EL) {
        atomicAdd(&counts[eil[EL + idx]], 1);
    } else if (idx < EL + EG) {
        int j = idx - EL;
        atomicAdd(&counts[n + eig[EG + j]], 1);
    }
}

// single block, 1024 threads; chunk=32 kept in REGISTERS (int4 x8).
__global__ __launch_bounds__(1024) void scan_kernel(
    const int* __restrict__ counts, int n2,
    int* __restrict__ rowStart, int* __restrict__ cursor)
{
    __shared__ int wsum[16];
    const int t = threadIdx.x;
    const int chunk = n2 >> 10;            // 32
    const int base = t * chunk;

    int4 c[8];
    const int4* c4 = reinterpret_cast<const int4*>(counts + base);
    #pragma unroll
    for (int i = 0; i < 8; ++i) c[i] = c4[i];

    int s = 0;
    #pragma unroll
    for (int i = 0; i < 8; ++i) s += c[i].x + c[i].y + c[i].z + c[i].w;

    const int lane = t & 63, w = t >> 6;
    int sc = s;
    #pragma unroll
    for (int off = 1; off < 64; off <<= 1) {
        int xv = __shfl_up(sc, off);
        if (lane >= off) sc += xv;
    }
    if (lane == 63) wsum[w] = sc;
    __syncthreads();
    int woff = 0;
    for (int i = 0; i < w; ++i) woff += wsum[i];
    int off = woff + sc - s;               // exclusive prefix of this chunk

    #pragma unroll
    for (int i = 0; i < 8; ++i) {
        int v0 = c[i].x, v1 = c[i].y, v2 = c[i].z, v3 = c[i].w;
        int o0 = off, o1 = o0 + v0, o2 = o1 + v1, o3 = o2 + v2;
        *reinterpret_cast<int4*>(rowStart + base + i * 4) = make_int4(o0, o1, o2, o3);
        *reinterpret_cast<int4*>(cursor   + base + i * 4) = make_int4(o0, o1, o2, o3);
        off = o3 + v3;
    }
    if (t == 1023) rowStart[n2] = off;
}

// ---------------------------------------------------------------------------
// Fused scatter + geometry: one pass over all EL+EG edges.
// ---------------------------------------------------------------------------
__global__ __launch_bounds__(256) void scatgeom_kernel(
    const int* __restrict__ eil, const int* __restrict__ eal, int EL,
    const int* __restrict__ eig, const int* __restrict__ eag, int EG,
    int* __restrict__ cursor, int n,
    const float* __restrict__ pos, const unsigned short* __restrict__ bondbf,
    int2* __restrict__ st2, float4* __restrict__ rn4,
    unsigned short* __restrict__ rbfb)
{
    int idx = blockIdx.x * 256 + threadIdx.x;
    if (idx >= EL + EG) return;
    int src, tgt, ea, cbase;
    float cutoff;
    if (idx < EL) {
        src = eil[idx]; tgt = eil[EL + idx]; ea = eal[idx];
        cbase = 0; cutoff = 3.0f;
    } else {
        int j = idx - EL;
        src = eig[j]; tgt = eig[EG + j]; ea = eag[j];
        cbase = n; cutoff = 10.0f;
    }
    int p = atomicAdd(&cursor[cbase + tgt], 1);
    st2[p] = make_int2(src, tgt);

    float rx = pos[3*tgt]-pos[3*src], ry = pos[3*tgt+1]-pos[3*src+1], rz = pos[3*tgt+2]-pos[3*src+2];
    float d = sqrtf(fmaxf(rx*rx + ry*ry + rz*rz, 1e-6f));
    float invd = 1.0f / d;
    rn4[p] = make_float4(rx*invd, ry*invd, rz*invd, d);
    float env = (d < cutoff) ? 0.5f * (__cosf(3.14159265358979f * d / cutoff) + 1.0f) : 0.0f;
    float invw = (float)RDdim / cutoff;
    unsigned int pk[8];
    #pragma unroll
    for (int i2 = 0; i2 < 8; ++i2) {
        float c0 = cutoff * ((float)(2*i2)     / 15.0f);
        float c1 = cutoff * ((float)(2*i2 + 1) / 15.0f);
        float t0 = (d - c0) * invw, t1 = (d - c1) * invw;
        unsigned short b0 = f2bf(__expf(-0.5f * t0 * t0) * env);
        unsigned short b1 = f2bf(__expf(-0.5f * t1 * t1) * env);
        pk[i2] = (unsigned)b0 | ((unsigned)b1 << 16);
    }
    uint4* o = reinterpret_cast<uint4*>(rbfb + (size_t)p * 32);
    o[0] = make_uint4(pk[0], pk[1], pk[2], pk[3]);
    o[1] = make_uint4(pk[4], pk[5], pk[6], pk[7]);
    const uint4* bp = reinterpret_cast<const uint4*>(bondbf + ea * EDdim);
    o[2] = bp[0];
    o[3] = bp[1];
}

// ---------------------------------------------------------------------------
// Kernel A: edge MLP as a pure tall-skinny GEMM.
// ---------------------------------------------------------------------------
__global__ __launch_bounds__(256) void edge_mlp_kernel(
    const unsigned short* __restrict__ sbf_in,
    const int2* __restrict__ st2,
    const unsigned short* __restrict__ rbfb,
    const unsigned short* __restrict__ wpk,
    const float* __restrict__ bg,
    unsigned short* __restrict__ hm,
    unsigned short* __restrict__ hv,
    int eOff)
{
    __shared__ __align__(16) unsigned short Wl[FINdim * Hdim];  // 30720 B
    {
        const uint4* s4 = reinterpret_cast<const uint4*>(wpk);
        uint4* d4 = reinterpret_cast<uint4*>(Wl);
        for (int i = threadIdx.x; i < FINdim * Hdim / 8; i += 256) d4[i] = s4[i];
    }
    __syncthreads();

    const int lane = threadIdx.x & 63;
    const int wid  = threadIdx.x >> 6;
    const int l15 = lane & 15, l4 = lane >> 4;
    const int base0 = eOff + blockIdx.x * 128 + wid * 16;
    const int base1 = base0 + 64;

    const int2 st0 = st2[base0 + l15];
    const int2 st1 = st2[base1 + l15];
    bf16x8 a0[5], a1[5];
    {
        const unsigned short* sp = sbf_in + (size_t)st0.x * Sdim;
        const unsigned short* tp = sbf_in + (size_t)st0.y * Sdim;
        a0[0] = *reinterpret_cast<const bf16x8*>(sp + l4 * 8);
        a0[1] = *reinterpret_cast<const bf16x8*>(sp + 32 + l4 * 8);
        a0[2] = *reinterpret_cast<const bf16x8*>(tp + l4 * 8);
        a0[3] = *reinterpret_cast<const bf16x8*>(tp + 32 + l4 * 8);
        a0[4] = *reinterpret_cast<const bf16x8*>(rbfb + (size_t)(base0 + l15) * 32 + l4 * 8);
    }
    {
        const unsigned short* sp = sbf_in + (size_t)st1.x * Sdim;
        const unsigned short* tp = sbf_in + (size_t)st1.y * Sdim;
        a1[0] = *reinterpret_cast<const bf16x8*>(sp + l4 * 8);
        a1[1] = *reinterpret_cast<const bf16x8*>(sp + 32 + l4 * 8);
        a1[2] = *reinterpret_cast<const bf16x8*>(tp + l4 * 8);
        a1[3] = *reinterpret_cast<const bf16x8*>(tp + 32 + l4 * 8);
        a1[4] = *reinterpret_cast<const bf16x8*>(rbfb + (size_t)(base1 + l15) * 32 + l4 * 8);
    }

    f32x4 acc0[6], acc1[6];
    #pragma unroll
    for (int nt = 0; nt < 6; ++nt) {
        acc0[nt] = (f32x4){0.f, 0.f, 0.f, 0.f};
        acc1[nt] = (f32x4){0.f, 0.f, 0.f, 0.f};
    }
    #pragma unroll
    for (int kk = 0; kk < 5; ++kk) {
        #pragma unroll
        for (int nt = 0; nt < 6; ++nt) {
            bf16x8 b = *reinterpret_cast<const bf16x8*>(
                Wl + ((size_t)(kk * 4 + l4) * Hdim + nt * 16 + l15) * 8);
            acc0[nt] = __builtin_amdgcn_mfma_f32_16x16x32_bf16(a0[kk], b, acc0[nt], 0, 0, 0);
            acc1[nt] = __builtin_amdgcn_mfma_f32_16x16x32_bf16(a1[kk], b, acc1[nt], 0, 0, 0);
        }
    }

    #pragma unroll
    for (int nt = 0; nt < 6; ++nt) {
        const float bs = bg[nt * 16 + l15];
        #pragma unroll
        for (int r = 0; r < 4; ++r) {
            const int e0 = base0 + l4 * 4 + r;
            const int e1 = base1 + l4 * 4 + r;
            const unsigned short h0 = f2bf(silu_f(acc0[nt][r] + bs));
            const unsigned short h1 = f2bf(silu_f(acc1[nt][r] + bs));
            if (nt < 4) {
                hm[(size_t)e0 * 64 + nt * 16 + l15] = h0;
                hm[(size_t)e1 * 64 + nt * 16 + l15] = h1;
            } else {
                hv[(size_t)e0 * 32 + (nt - 4) * 16 + l15] = h0;
                hv[(size_t)e1 * 32 + (nt - 4) * 16 + l15] = h1;
            }
        }
    }
}

// ---------------------------------------------------------------------------
// Kernel B: ONE WAVE PER NODE, x2 edge unroll (explicit temporaries, r14
// measured optimum) + 4-way split update-GEMM (chain 64 -> 16); fused head1
// on the last layer-set.
// ---------------------------------------------------------------------------
__global__ __launch_bounds__(64) void node_agg_kernel(
    const float* __restrict__ s_in, float* __restrict__ s_out,
    unsigned short* __restrict__ sbf_out,
    const float* __restrict__ v_in, float* __restrict__ v_out,
    const int* __restrict__ rowStart, const int2* __restrict__ st2,
    const float* __restrict__ rn4f,
    const unsigned short* __restrict__ hm, const unsigned short* __restrict__ hv,
    const float* __restrict__ wu, const float* __restrict__ bu,
    const float* __restrict__ lng, const float* __restrict__ lnb,
    int do_ln, int v_zero,
    int do_head, const float* __restrict__ wd, const float* __restrict__ wo,
    float* __restrict__ dsc, float* __restrict__ out)
{
    const int node = blockIdx.x;
    const int lane = threadIdx.x;
    const int l15 = lane & 15, dd = lane >> 4;
    const int lo = rowStart[node], hi = rowStart[node + 1];
    const float bulane = bu[lane];

    float msum0 = 0.0f, msum1 = 0.0f, vsum0 = 0.0f, vsum1 = 0.0f;
    int e = lo;
    for (; e + 1 < hi; e += 2) {
        msum0 += bf2f(hm[(size_t)e * 64 + lane]);
        msum1 += bf2f(hm[(size_t)(e + 1) * 64 + lane]);
        if (lane < NVdim) {
            float wv1a = bf2f(hv[(size_t)e * 32 + l15]);
            float wv2a = bf2f(hv[(size_t)e * 32 + 16 + l15]);
            float rnda = rn4f[(size_t)e * 4 + dd];
            float wv1b = bf2f(hv[(size_t)(e + 1) * 32 + l15]);
            float wv2b = bf2f(hv[(size_t)(e + 1) * 32 + 16 + l15]);
            float rndb = rn4f[(size_t)(e + 1) * 4 + dd];
            vsum0 = fmaf(rnda, wv2a, vsum0);
            vsum1 = fmaf(rndb, wv2b, vsum1);
            if (!v_zero) {
                float vva = v_in[(size_t)st2[e].x * NVdim + lane];
                float vvb = v_in[(size_t)st2[e + 1].x * NVdim + lane];
                vsum0 = fmaf(vva, wv1a, vsum0);
                vsum1 = fmaf(vvb, wv1b, vsum1);
            }
        }
    }
    if (e < hi) {
        msum0 += bf2f(hm[(size_t)e * 64 + lane]);
        if (lane < NVdim) {
            float wv1 = bf2f(hv[(size_t)e * 32 + l15]);
            float wv2 = bf2f(hv[(size_t)e * 32 + 16 + l15]);
            float rnd = rn4f[(size_t)e * 4 + dd];
            vsum0 = fmaf(rnd, wv2, vsum0);
            if (!v_zero) {
                float vv = v_in[(size_t)st2[e].x * NVdim + lane];
                vsum0 = fmaf(vv, wv1, vsum0);
            }
        }
    }
    float msum = msum0 + msum1;
    float vsum = vsum0 + vsum1;

    __shared__ float ag[64];
    const float ic = 1.0f / fmaxf((float)(hi - lo), 1.0f);
    ag[lane] = msum * ic;            // single wave: in-order LDS, no barrier

    // update GEMM: 4 independent 16-deep chains (explicit accumulators)
    float d0 = 0.0f, d1 = 0.0f, d2 = 0.0f, d3 = 0.0f;
    #pragma unroll 4
    for (int i = 0; i < 16; ++i) {
        d0 = fmaf(ag[i],      wu[(i)      * Sdim + lane], d0);
        d1 = fmaf(ag[i + 16], wu[(i + 16) * Sdim + lane], d1);
        d2 = fmaf(ag[i + 32], wu[(i + 32) * Sdim + lane], d2);
        d3 = fmaf(ag[i + 48], wu[(i + 48) * Sdim + lane], d3);
    }
    float dot = (d0 + d1) + (d2 + d3);

    float sn = s_in[(size_t)node * Sdim + lane] + silu_f(dot + bulane);
    if (do_ln) {
        float mm = sn;
        #pragma unroll
        for (int off = 32; off >= 1; off >>= 1) mm += __shfl_xor(mm, off);
        mm *= (1.0f / 64.0f);
        float dv = sn - mm;
        float var = dv * dv;
        #pragma unroll
        for (int off = 32; off >= 1; off >>= 1) var += __shfl_xor(var, off);
        var *= (1.0f / 64.0f);
        sn = dv * rsqrtf(var + 1e-5f) * lng[lane] + lnb[lane];
    }
    s_out[(size_t)node * Sdim + lane]   = sn;
    sbf_out[(size_t)node * Sdim + lane] = f2bf(sn);
    float vnew = 0.0f;
    if (lane < NVdim) {
        float vprev = v_zero ? 0.0f : v_in[(size_t)node * NVdim + lane];
        vnew = vprev + vsum * ic;
        v_out[(size_t)node * NVdim + lane] = vnew;
    }

    if (do_head) {
        float val = silu_f(sn) * wd[lane];
        #pragma unroll
        for (int off = 32; off >= 1; off >>= 1) val += __shfl_xor(val, off);
        if (lane == 0) dsc[node] = val;
        float contrib = (lane < NVdim) ? vnew * wo[l15] : 0.0f;
        #pragma unroll
        for (int off = 1; off < 16; off <<= 1) contrib += __shfl_xor(contrib, off);
        if (lane < NVdim && l15 == 0) out[(size_t)node * 3 + dd] = contrib;
    }
}

// ---------------------------------------------------------------------------
// head2: node-parallel over CSR-G; no atomics.  pos[src]-pos[tgt] = -rn*d.
// ---------------------------------------------------------------------------
__global__ __launch_bounds__(256) void head2_kernel(
    const float* __restrict__ dsc, const int* __restrict__ rsG,
    const int2* __restrict__ st2, const float4* __restrict__ rn4,
    float* __restrict__ out, int n)
{
    int t = blockIdx.x * 256 + threadIdx.x;
    if (t >= n) return;
    int lo = rsG[t], hi = rsG[t + 1];
    float dt = dsc[t];
    float ax = 0.f, ay = 0.f, az = 0.f;
    for (int e = lo; e < hi; ++e) {
        float w = dsc[st2[e].x] + dt;
        float4 rn = rn4[e];
        float wd_ = w * rn.w;
        ax -= wd_ * rn.x; ay -= wd_ * rn.y; az -= wd_ * rn.z;
    }
    out[3 * t + 0] += ax;
    out[3 * t + 1] += ay;
    out[3 * t + 2] += az;
}

// ---------------------------------------------------------------------------
extern "C" void kernel_launch(void* const* d_in, const int* in_sizes, int n_in,
                              void* d_out, int out_size, void* d_ws, size_t ws_size,
                              hipStream_t stream)
{
    const int*   x     = (const int*)d_in[0];
    const float* t     = (const float*)d_in[1];
    const float* pos   = (const float*)d_in[2];
    const int*   eil   = (const int*)d_in[3];
    const int*   eig   = (const int*)d_in[4];
    const int*   eal   = (const int*)d_in[5];
    const int*   eag   = (const int*)d_in[6];
    const int*   batch = (const int*)d_in[7];
    const float* aemb  = (const float*)d_in[8];
    const float* bemb  = (const float*)d_in[9];
    const float* t_w1  = (const float*)d_in[10];
    const float* t_b1  = (const float*)d_in[11];
    const float* t_w2  = (const float*)d_in[12];
    const float* t_b2  = (const float*)d_in[13];
    const float* wm    = (const float*)d_in[14];
    const float* bm    = (const float*)d_in[15];
    const float* wu    = (const float*)d_in[16];
    const float* bu    = (const float*)d_in[17];
    const float* lng   = (const float*)d_in[18];
    const float* lnb   = (const float*)d_in[19];
    const float* wd    = (const float*)d_in[20];
    const float* wo    = (const float*)d_in[21];

    const int n  = in_sizes[7];          // 16384
    const int B  = in_sizes[1] / TDdim;  // 64
    const int EL = in_sizes[3] / 2;      // 131072
    const int EG = in_sizes[4] / 2;      // 262144
    const int ET = EL + EG;

    // ---- workspace layout ----
    char* p = (char*)d_ws;
    auto alignup = [](char* q) { return (char*)(((size_t)q + 15) & ~(size_t)15); };

    float* temb = (float*)p;                 p += (size_t)B * Sdim * 4;
    float* dsc  = (float*)p;                 p += (size_t)n * 4;
    float* sA   = (float*)p;                 p += (size_t)n * Sdim * 4;
    float* sB   = (float*)p;                 p += (size_t)n * Sdim * 4;
    float* vA   = (float*)p;                 p += (size_t)n * NVdim * 4;
    float* vB   = (float*)p;                 p += (size_t)n * NVdim * 4;
    int* counts = (int*)p;                   p += (size_t)(2 * n) * 4;
    int* cursor = (int*)p;                   p += (size_t)(2 * n) * 4;
    int* rsAll  = (int*)p;                   p += (size_t)(2 * n + 4) * 4;
    p = alignup(p);
    int2* st2   = (int2*)p;                  p += (size_t)ET * 8;
    p = alignup(p);
    unsigned short* wp     = (unsigned short*)p;  p += (size_t)10 * FINdim * Hdim * 2;
    p = alignup(p);
    unsigned short* bondbf = (unsigned short*)p;  p += 96 * 2;
    p = alignup(p);
    unsigned short* sbfA   = (unsigned short*)p;  p += (size_t)n * Sdim * 2;
    unsigned short* sbfB   = (unsigned short*)p;  p += (size_t)n * Sdim * 2;
    p = alignup(p);
    float4* rn4 = (float4*)p;                p += (size_t)ET * 16;
    unsigned short* rbfb = (unsigned short*)p;    p += (size_t)ET * 32 * 2;
    p = alignup(p);
    unsigned short* hm = (unsigned short*)p; p += (size_t)ET * 64 * 2;
    unsigned short* hv = (unsigned short*)p; p += (size_t)ET * 32 * 2;

    float* out = (float*)d_out;

    // ---- precompute packed weights + init (pack also zeroes counts) ----
    pack_kernel<<<(10 * FINdim * Hdim + 80 + 255) / 256, 256, 0, stream>>>(
        wm, bemb, wp, bondbf, counts, 2 * n);
    temb_kernel<<<B, 64, 0, stream>>>(t, t_w1, t_b1, t_w2, t_b2, temb);
    node_init_kernel<<<(n * Sdim + 255) / 256, 256, 0, stream>>>(x, batch, aemb, temb, sA, sbfA, n);

    // ---- combined CSR build + geometry ----
    count_all_kernel<<<(ET + 255) / 256, 256, 0, stream>>>(eil, EL, eig, EG, counts, n);
    scan_kernel<<<1, 1024, 0, stream>>>(counts, 2 * n, rsAll, cursor);
    scatgeom_kernel<<<(ET + 255) / 256, 256, 0, stream>>>(
        eil, eal, EL, eig, eag, EG, cursor, n, pos, bondbf, st2, rn4, rbfb);

    // ---- layers: edge-MLP GEMM then node aggregate/update ----
    float* s_cur = sA; float* s_nxt = sB;
    float* v_cur = vA; float* v_nxt = vB;
    unsigned short* sb_cur = sbfA; unsigned short* sb_nxt = sbfB;

    for (int l = 0; l < NLAYER; ++l) {
        for (int k = 0; k < 2; ++k) {
            int ls = l * 2 + k;
            const unsigned short* wpk = wp + (size_t)ls * FINdim * Hdim;
            const float* bgk = bm + (size_t)ls * Hdim;
            const float* wuk = wu + (size_t)ls * Sdim * Sdim;
            const float* buk = bu + (size_t)ls * Sdim;
            const int E    = (k == 0) ? EL : EG;
            const int eOff = (k == 0) ? 0 : EL;
            const int* rsk = (k == 0) ? rsAll : rsAll + n;
            const int v_zero = (l == 0 && k == 0) ? 1 : 0;
            const int is_last = (l == NLAYER - 1 && k == 1) ? 1 : 0;

            edge_mlp_kernel<<<E / 128, 256, 0, stream>>>(
                sb_cur, st2, rbfb, wpk, bgk, hm, hv, eOff);
            node_agg_kernel<<<n, 64, 0, stream>>>(
                s_cur, s_nxt, sb_nxt, v_cur, v_nxt,
                rsk, st2, (const float*)rn4, hm, hv,
                wuk, buk, lng + (size_t)l * Sdim, lnb + (size_t)l * Sdim,
                (k == 1) ? 1 : 0, v_zero,
                is_last, wd, wo, dsc, out);

            float* tmp = s_cur; s_cur = s_nxt; s_nxt = tmp;
            tmp = v_cur; v_cur = v_nxt; v_nxt = tmp;
            unsigned short* tb = sb_cur; sb_cur = sb_nxt; sb_nxt = tb;
        }
    }

    head2_kernel<<<(n + 255) / 256, 256, 0, stream>>>(dsc, rsAll + n, st2, rn4, out, n);
}